// Round 5
// baseline (319.695 us; speedup 1.0000x reference)
//
#include <hip/hip_runtime.h>
#include <hip/hip_bf16.h>

typedef __attribute__((ext_vector_type(8))) short bfrag_t;
typedef __attribute__((ext_vector_type(4))) float facc_t;

#define B_ 4
#define S_ 4096
#define D_ 256

using gas_v = const __attribute__((address_space(1))) void;
using las_v = __attribute__((address_space(3))) void;

__device__ __forceinline__ short f2bf(float f) {
  union { float fv; unsigned u; } x; x.fv = f;
  unsigned r = x.u + 0x7FFFu + ((x.u >> 16) & 1u);
  return (short)(r >> 16);
}

__device__ __forceinline__ facc_t mfma16(bfrag_t a, bfrag_t b, facc_t c) {
  return __builtin_amdgcn_mfma_f32_16x16x32_bf16(a, b, c, 0, 0, 0);
}

// ---- transpose weights to bf16: WT[p][e][d] = W_p[d][e] --------------------
__global__ void wt_kernel(const float* __restrict__ Wq, const float* __restrict__ Wk,
                          const float* __restrict__ Wv, short* __restrict__ WT) {
  const int p = blockIdx.x >> 4;
  const float* W = (p == 0) ? Wq : ((p == 1) ? Wk : Wv);
  short* o = WT + p * (D_ * D_);
  const int e = (blockIdx.x & 15) * 16 + (threadIdx.x >> 4);
  const int td = threadIdx.x & 15;
  #pragma unroll
  for (int dd = 0; dd < 16; ++dd) {
    int d = td * 16 + dd;
    o[e * D_ + d] = f2bf(W[d * D_ + e]);
  }
}

// ---- QKV projection: one projection per block (p = bid>>8) -----------------
__global__ __launch_bounds__(256) void proj_kernel(
    const float* __restrict__ X, const short* __restrict__ WT,
    short* __restrict__ Qb, short* __restrict__ Kb, short* __restrict__ VT) {
  __shared__ __align__(16) short Vt[256 * 72];    // V transpose buffer (36.9 KB)
  const int tid  = threadIdx.x;
  const int wave = tid >> 6, lane = tid & 63;
  const int lrow = lane & 15, kch = lane >> 4;
  const int p  = blockIdx.x >> 8;
  const int rb = blockIdx.x & 255;
  const int row0 = rb * 64 + wave * 16;
  const int arow = row0 + lrow;
  const int bblk = rb >> 6;                       // batch index

  bfrag_t af[8];
  #pragma unroll
  for (int kt = 0; kt < 8; ++kt) {
    const float* src = X + (size_t)arow * D_ + kt * 32 + kch * 8;
    float4 a = *reinterpret_cast<const float4*>(src);
    float4 b = *reinterpret_cast<const float4*>(src + 4);
    bfrag_t f;
    f[0] = f2bf(a.x); f[1] = f2bf(a.y); f[2] = f2bf(a.z); f[3] = f2bf(a.w);
    f[4] = f2bf(b.x); f[5] = f2bf(b.y); f[6] = f2bf(b.z); f[7] = f2bf(b.w);
    af[kt] = f;
  }

  const short* Wp = WT + p * (D_ * D_);
  facc_t acc[16];
  #pragma unroll
  for (int nt = 0; nt < 16; ++nt) acc[nt] = (facc_t)0.0f;
  #pragma unroll
  for (int kt = 0; kt < 8; ++kt) {
    #pragma unroll
    for (int nt = 0; nt < 16; ++nt) {
      bfrag_t bf = *reinterpret_cast<const bfrag_t*>(
          Wp + (nt * 16 + lrow) * D_ + kt * 32 + kch * 8);
      acc[nt] = mfma16(af[kt], bf, acc[nt]);
    }
  }
  if (p == 0) {
    #pragma unroll
    for (int nt = 0; nt < 16; ++nt)
      #pragma unroll
      for (int r = 0; r < 4; ++r)
        Qb[(size_t)(row0 + kch * 4 + r) * D_ + nt * 16 + lrow] =
            f2bf(acc[nt][r] * 0.0625f);   // fold 1/sqrt(256)
  } else if (p == 1) {
    #pragma unroll
    for (int nt = 0; nt < 16; ++nt)
      #pragma unroll
      for (int r = 0; r < 4; ++r)
        Kb[(size_t)(row0 + kch * 4 + r) * D_ + nt * 16 + lrow] = f2bf(acc[nt][r]);
  } else {
    // V: transpose through LDS, then 16B-chunk global writes
    #pragma unroll
    for (int nt = 0; nt < 16; ++nt)
      #pragma unroll
      for (int r = 0; r < 4; ++r)
        Vt[(nt * 16 + lrow) * 72 + wave * 16 + kch * 4 + r] = f2bf(acc[nt][r]);
    __syncthreads();
    const int d = tid;
    const int s0 = (rb & 63) * 64;
    short* dst = VT + ((size_t)(bblk * D_ + d)) * S_ + s0;
    #pragma unroll
    for (int j = 0; j < 8; ++j)
      *reinterpret_cast<bfrag_t*>(dst + j * 8) =
          *reinterpret_cast<const bfrag_t*>(&Vt[d * 72 + j * 8]);
  }
}

// ---- flash attention: 256 blocks x 4 waves, KVBLK=32, dbuf LDS, 2 blk/CU ---
__global__ __launch_bounds__(256, 2) void attn_kernel(
    const short* __restrict__ Qb, const short* __restrict__ Kb,
    const short* __restrict__ VT, float* __restrict__ Out) {
  // K tile [32 kv][256 d] (512B rows, byte ^= (row&7)<<4)
  // V tile [256 d][32 kv] (64B rows,  byte ^= ((d>>1)&3)<<4)
  __shared__ __align__(16) short Kl[2][32 * 256];
  __shared__ __align__(16) short Vl[2][256 * 32];
  __shared__ __align__(16) short Pl[4][16][40];   // 80B rows (16B-aligned)
  const int tid  = threadIdx.x;
  const int wave = tid >> 6, lane = tid & 63;
  const int lrow = lane & 15, kch = lane >> 4;
  const int rs = (lrow & 7) << 4;                 // K-read swizzle
  const int vs = ((lrow >> 1) & 3) << 4;          // V-read swizzle
  // bijective XCD-chunked swizzle (nwg=256): XCD x -> 32 consecutive q-tiles
  const int bid = ((blockIdx.x & 7) << 5) | (blockIdx.x >> 3);
  const int b  = bid >> 6;                        // 64 blocks per batch
  const int q0 = (bid & 63) * 64 + wave * 16;     // wave's q-rows in batch

  const short* Kbp = Kb + (size_t)b * S_ * D_;
  const short* Vbp = VT + (size_t)b * D_ * S_;

  // hoist Q A-frags
  bfrag_t qf[8];
  #pragma unroll
  for (int kt = 0; kt < 8; ++kt)
    qf[kt] = *reinterpret_cast<const bfrag_t*>(
        Qb + ((size_t)b * S_ + q0 + lrow) * D_ + kt * 32 + kch * 8);

  // stage one 32-kv tile (K 16KB + V 16KB), 8 x 16B DMA per thread
  auto stage = [&](int bf, int kv0) {
    #pragma unroll
    for (int j = 0; j < 4; ++j) {
      int L = j * 4096 + tid * 16;
      int row = L >> 9;
      int colb = (L & 511) ^ ((row & 7) << 4);    // inverse-swizzled source
      const short* src = Kbp + (size_t)(kv0 + row) * D_ + (colb >> 1);
      short* dst = &Kl[bf][(j * 4096 + wave * 1024) >> 1];
      __builtin_amdgcn_global_load_lds((gas_v*)src, (las_v*)dst, 16, 0, 0);
    }
    #pragma unroll
    for (int j = 0; j < 4; ++j) {
      int L = j * 4096 + tid * 16;
      int d = L >> 6;
      int colb = (L & 63) ^ (((d >> 1) & 3) << 4);
      const short* src = Vbp + (size_t)d * S_ + kv0 + (colb >> 1);
      short* dst = &Vl[bf][(j * 4096 + wave * 1024) >> 1];
      __builtin_amdgcn_global_load_lds((gas_v*)src, (las_v*)dst, 16, 0, 0);
    }
  };

  facc_t oacc[16];
  #pragma unroll
  for (int nt = 0; nt < 16; ++nt) oacc[nt] = (facc_t)0.0f;
  float mrow[4], lsum[4];
  #pragma unroll
  for (int r = 0; r < 4; ++r) { mrow[r] = -3.0e38f; lsum[r] = 0.0f; }

  stage(0, 0);
  asm volatile("s_waitcnt vmcnt(0)" ::: "memory");
  __syncthreads();
  int buf = 0;

  #pragma unroll 1
  for (int t = 0; t < 128; ++t) {
    if (t < 127) stage(buf ^ 1, (t + 1) * 32);    // issue-early prefetch
    // ---- scores S = Q K^T (Q pre-scaled) ----
    facc_t sacc[2];
    sacc[0] = (facc_t)0.0f; sacc[1] = (facc_t)0.0f;
    const char* Kbase = (const char*)&Kl[buf][0];
    __builtin_amdgcn_s_setprio(1);
    #pragma unroll
    for (int kt = 0; kt < 8; ++kt) {
      #pragma unroll
      for (int nt = 0; nt < 2; ++nt) {
        int row = nt * 16 + lrow;
        bfrag_t kf = *reinterpret_cast<const bfrag_t*>(
            Kbase + row * 512 + ((kt * 64 + kch * 16) ^ rs));
        sacc[nt] = mfma16(qf[kt], kf, sacc[nt]);
      }
    }
    __builtin_amdgcn_s_setprio(0);
    // ---- online softmax (rows r in regs, cols across 16-lane group) ----
    float pv[2][4];
    float sf[4];
    #pragma unroll
    for (int r = 0; r < 4; ++r) {
      float mx = fmaxf(sacc[0][r], sacc[1][r]);
      mx = fmaxf(mx, __shfl_xor(mx, 1));
      mx = fmaxf(mx, __shfl_xor(mx, 2));
      mx = fmaxf(mx, __shfl_xor(mx, 4));
      mx = fmaxf(mx, __shfl_xor(mx, 8));
      float mn = fmaxf(mrow[r], mx);
      sf[r] = __expf(mrow[r] - mn);
      mrow[r] = mn;
      float e0 = __expf(sacc[0][r] - mn);
      float e1 = __expf(sacc[1][r] - mn);
      pv[0][r] = e0; pv[1][r] = e1;
      float s = e0 + e1;
      s += __shfl_xor(s, 1); s += __shfl_xor(s, 2);
      s += __shfl_xor(s, 4); s += __shfl_xor(s, 8);
      lsum[r] = lsum[r] * sf[r] + s;
    }
    facc_t sfv;
    sfv[0] = sf[0]; sfv[1] = sf[1]; sfv[2] = sf[2]; sfv[3] = sf[3];
    #pragma unroll
    for (int nt = 0; nt < 16; ++nt) oacc[nt] *= sfv;
    // ---- P -> LDS (C-layout write), read back as A-frag ----
    #pragma unroll
    for (int nt = 0; nt < 2; ++nt)
      #pragma unroll
      for (int r = 0; r < 4; ++r)
        Pl[wave][kch * 4 + r][nt * 16 + lrow] = f2bf(pv[nt][r]);
    asm volatile("s_waitcnt lgkmcnt(0)" ::: "memory");
    __builtin_amdgcn_sched_barrier(0);
    bfrag_t pf = *reinterpret_cast<const bfrag_t*>(&Pl[wave][lrow][kch * 8]);
    // ---- O += P V ----
    const char* Vbase = (const char*)&Vl[buf][0];
    __builtin_amdgcn_s_setprio(1);
    #pragma unroll
    for (int nt = 0; nt < 16; ++nt) {
      int d = nt * 16 + lrow;
      bfrag_t vf = *reinterpret_cast<const bfrag_t*>(
          Vbase + d * 64 + ((kch * 16) ^ vs));
      oacc[nt] = mfma16(pf, vf, oacc[nt]);
    }
    __builtin_amdgcn_s_setprio(0);
    asm volatile("s_waitcnt vmcnt(0)" ::: "memory");  // prefetch landed
    __syncthreads();
    buf ^= 1;
  }

  // ---- epilogue: normalize and store fp32 ----
  float inv[4];
  #pragma unroll
  for (int r = 0; r < 4; ++r) inv[r] = 1.0f / lsum[r];
  #pragma unroll
  for (int nt = 0; nt < 16; ++nt)
    #pragma unroll
    for (int r = 0; r < 4; ++r)
      Out[((size_t)b * S_ + q0 + kch * 4 + r) * D_ + nt * 16 + lrow] =
          oacc[nt][r] * inv[r];
}

extern "C" void kernel_launch(void* const* d_in, const int* in_sizes, int n_in,
                              void* d_out, int out_size, void* d_ws, size_t ws_size,
                              hipStream_t stream) {
  const float* X  = (const float*)d_in[0];
  const float* Wq = (const float*)d_in[1];
  const float* Wk = (const float*)d_in[2];
  const float* Wv = (const float*)d_in[3];
  float* out = (float*)d_out;

  char* ws = (char*)d_ws;
  short* Qb = (short*)(ws);                       // 8 MB
  short* Kb = (short*)(ws + 8388608);             // 8 MB
  short* VT = (short*)(ws + 16777216);            // 8 MB (V transposed [B][D][S])
  short* WT = (short*)(ws + 25165824);            // 384 KB

  wt_kernel<<<48, 256, 0, stream>>>(Wq, Wk, Wv, WT);
  proj_kernel<<<768, 256, 0, stream>>>(X, WT, Qb, Kb, VT);
  attn_kernel<<<256, 256, 0, stream>>>(Qb, Kb, VT, out);
}

// Round 6
// 251.665 us; speedup vs baseline: 1.2703x; 1.2703x over previous
//
#include <hip/hip_runtime.h>
#include <hip/hip_bf16.h>

typedef __attribute__((ext_vector_type(8))) short bfrag_t;
typedef __attribute__((ext_vector_type(4))) float facc_t;
typedef __attribute__((ext_vector_type(2))) int i2_t;
typedef __attribute__((ext_vector_type(4))) int i4_t;

#define B_ 4
#define S_ 4096
#define D_ 256

using gas_v = const __attribute__((address_space(1))) void;
using las_v = __attribute__((address_space(3))) void;

__device__ __forceinline__ short f2bf(float f) {
  union { float fv; unsigned u; } x; x.fv = f;
  unsigned r = x.u + 0x7FFFu + ((x.u >> 16) & 1u);
  return (short)(r >> 16);
}

__device__ __forceinline__ facc_t mfma16(bfrag_t a, bfrag_t b, facc_t c) {
  return __builtin_amdgcn_mfma_f32_16x16x32_bf16(a, b, c, 0, 0, 0);
}

// ---- transpose weights to bf16: WT[p][e][d] = W_p[d][e] --------------------
__global__ void wt_kernel(const float* __restrict__ Wq, const float* __restrict__ Wk,
                          const float* __restrict__ Wv, short* __restrict__ WT) {
  const int p = blockIdx.x >> 4;
  const float* W = (p == 0) ? Wq : ((p == 1) ? Wk : Wv);
  short* o = WT + p * (D_ * D_);
  const int e = (blockIdx.x & 15) * 16 + (threadIdx.x >> 4);
  const int td = threadIdx.x & 15;
  #pragma unroll
  for (int dd = 0; dd < 16; ++dd) {
    int d = td * 16 + dd;
    o[e * D_ + d] = f2bf(W[d * D_ + e]);
  }
}

// ---- QKV projection: one projection per block (p = bid>>8) -----------------
__global__ __launch_bounds__(256) void proj_kernel(
    const float* __restrict__ X, const short* __restrict__ WT,
    short* __restrict__ Qb, short* __restrict__ Kb, short* __restrict__ VT) {
  __shared__ __align__(16) short Vt[256 * 72];    // V transpose buffer
  const int tid  = threadIdx.x;
  const int wave = tid >> 6, lane = tid & 63;
  const int lrow = lane & 15, kch = lane >> 4;
  const int p  = blockIdx.x >> 8;
  const int rb = blockIdx.x & 255;
  const int row0 = rb * 64 + wave * 16;
  const int arow = row0 + lrow;
  const int bblk = rb >> 6;                       // batch index

  bfrag_t af[8];
  #pragma unroll
  for (int kt = 0; kt < 8; ++kt) {
    const float* src = X + (size_t)arow * D_ + kt * 32 + kch * 8;
    float4 a = *reinterpret_cast<const float4*>(src);
    float4 b = *reinterpret_cast<const float4*>(src + 4);
    bfrag_t f;
    f[0] = f2bf(a.x); f[1] = f2bf(a.y); f[2] = f2bf(a.z); f[3] = f2bf(a.w);
    f[4] = f2bf(b.x); f[5] = f2bf(b.y); f[6] = f2bf(b.z); f[7] = f2bf(b.w);
    af[kt] = f;
  }

  const short* Wp = WT + p * (D_ * D_);
  facc_t acc[16];
  #pragma unroll
  for (int nt = 0; nt < 16; ++nt) acc[nt] = (facc_t)0.0f;
  #pragma unroll
  for (int kt = 0; kt < 8; ++kt) {
    #pragma unroll
    for (int nt = 0; nt < 16; ++nt) {
      bfrag_t bf = *reinterpret_cast<const bfrag_t*>(
          Wp + (nt * 16 + lrow) * D_ + kt * 32 + kch * 8);
      acc[nt] = mfma16(af[kt], bf, acc[nt]);
    }
  }
  if (p == 0) {
    #pragma unroll
    for (int nt = 0; nt < 16; ++nt)
      #pragma unroll
      for (int r = 0; r < 4; ++r)
        Qb[(size_t)(row0 + kch * 4 + r) * D_ + nt * 16 + lrow] =
            f2bf(acc[nt][r] * 0.0625f);   // fold 1/sqrt(256)
  } else if (p == 1) {
    #pragma unroll
    for (int nt = 0; nt < 16; ++nt)
      #pragma unroll
      for (int r = 0; r < 4; ++r)
        Kb[(size_t)(row0 + kch * 4 + r) * D_ + nt * 16 + lrow] = f2bf(acc[nt][r]);
  } else {
    // V: transpose through LDS, then 16B-chunk global writes
    #pragma unroll
    for (int nt = 0; nt < 16; ++nt)
      #pragma unroll
      for (int r = 0; r < 4; ++r)
        Vt[(nt * 16 + lrow) * 72 + wave * 16 + kch * 4 + r] = f2bf(acc[nt][r]);
    __syncthreads();
    const int d = tid;
    const int s0 = (rb & 63) * 64;
    short* dst = VT + ((size_t)(bblk * D_ + d)) * S_ + s0;
    #pragma unroll
    for (int j = 0; j < 8; ++j)
      *reinterpret_cast<bfrag_t*>(dst + j * 8) =
          *reinterpret_cast<const bfrag_t*>(&Vt[d * 72 + j * 8]);
  }
}

// ---- flash attention, swapped-QK^T (lane owns one q-row), KVB=64, dbuf -----
// D = mfma(A=K, B=Q) -> S^T[kv][q]; softmax lane-local (2 shfls/step);
// P stays in regs as PV B-operand via k-map kv = g*4+(e&3)+16*(e>>2).
__global__ __launch_bounds__(256, 1) void attn_kernel(
    const short* __restrict__ Qb, const short* __restrict__ Kb,
    const short* __restrict__ VT, float* __restrict__ Out) {
  // K tile [64 kv][256 d] (512B rows, byte ^= (row&7)<<4)
  // V tile [256 d][64 kv] (128B rows, byte ^= (d&7)<<4)
  __shared__ __align__(16) short Kl[2][64 * 256];
  __shared__ __align__(16) short Vl[2][256 * 64];
  const int tid  = threadIdx.x;
  const int wave = tid >> 6, lane = tid & 63;
  const int lrow = lane & 15, kch = lane >> 4;
  const int sw = (lrow & 7) << 4;                 // K/V read swizzle (row&7==lrow&7)
  // bijective XCD-chunked swizzle (nwg=256)
  const int bid = ((blockIdx.x & 7) << 5) | (blockIdx.x >> 3);
  const int b  = bid >> 6;
  const int q0 = (bid & 63) * 64 + wave * 16;     // wave's q-rows in batch

  const short* Kbp = Kb + (size_t)b * S_ * D_;
  const short* Vbp = VT + (size_t)b * D_ * S_;

  // Q as B-operand: lane holds q-col lrow, k = kt*32 + kch*8 + e
  bfrag_t qf[8];
  #pragma unroll
  for (int kt = 0; kt < 8; ++kt)
    qf[kt] = *reinterpret_cast<const bfrag_t*>(
        Qb + ((size_t)b * S_ + q0 + lrow) * D_ + kt * 32 + kch * 8);

  // stage one 64-kv tile (K 32KB + V 32KB), 16 x 16B DMA per thread
  auto stage = [&](int bf, int kv0) {
    #pragma unroll
    for (int j = 0; j < 8; ++j) {
      int L = j * 4096 + tid * 16;
      int row = L >> 9;
      int cs = (L & 511) ^ ((row & 7) << 4);
      const short* src = Kbp + (size_t)(kv0 + row) * D_ + (cs >> 1);
      short* dst = &Kl[bf][(j * 4096 + wave * 1024) >> 1];
      __builtin_amdgcn_global_load_lds((gas_v*)src, (las_v*)dst, 16, 0, 0);
    }
    #pragma unroll
    for (int j = 0; j < 8; ++j) {
      int L = j * 4096 + tid * 16;
      int d = L >> 7;
      int cs = (L & 127) ^ ((d & 7) << 4);
      const short* src = Vbp + (size_t)d * S_ + kv0 + (cs >> 1);
      short* dst = &Vl[bf][(j * 4096 + wave * 1024) >> 1];
      __builtin_amdgcn_global_load_lds((gas_v*)src, (las_v*)dst, 16, 0, 0);
    }
  };

  facc_t oacc[16];
  #pragma unroll
  for (int nt = 0; nt < 16; ++nt) oacc[nt] = (facc_t)0.0f;
  float mrow = -3.0e38f, lsum = 0.0f;

  stage(0, 0);
  asm volatile("s_waitcnt vmcnt(0)" ::: "memory");
  __syncthreads();
  int buf = 0;

  #pragma unroll 1
  for (int t = 0; t < 64; ++t) {
    if (t < 63) stage(buf ^ 1, (t + 1) * 64);     // issue-early prefetch
    // ---- S^T = K Q^T : 4 kv-tiles x 8 kt ----
    facc_t sacc[4];
    #pragma unroll
    for (int nt = 0; nt < 4; ++nt) sacc[nt] = (facc_t)0.0f;
    const char* Kbase = (const char*)&Kl[buf][0];
    __builtin_amdgcn_s_setprio(1);
    #pragma unroll
    for (int kt = 0; kt < 8; ++kt) {
      #pragma unroll
      for (int nt = 0; nt < 4; ++nt) {
        int row = nt * 16 + lrow;
        bfrag_t kf = *reinterpret_cast<const bfrag_t*>(
            Kbase + row * 512 + ((kt * 64 + kch * 16) ^ sw));
        sacc[nt] = mfma16(kf, qf[kt], sacc[nt]);
      }
    }
    __builtin_amdgcn_s_setprio(0);
    // ---- softmax: lane owns q-row lrow, 16 kv values; 2 shfls ----
    float mx = fmaxf(fmaxf(sacc[0][0], sacc[0][1]), fmaxf(sacc[0][2], sacc[0][3]));
    #pragma unroll
    for (int nt = 1; nt < 4; ++nt)
      mx = fmaxf(mx, fmaxf(fmaxf(sacc[nt][0], sacc[nt][1]),
                           fmaxf(sacc[nt][2], sacc[nt][3])));
    mx = fmaxf(mx, __shfl_xor(mx, 16));
    mx = fmaxf(mx, __shfl_xor(mx, 32));
    if (mx > mrow + 8.0f) {                       // defer-max rescale
      float sf = __expf(mrow - mx);
      mrow = mx;
      lsum *= sf;
      #pragma unroll
      for (int nt = 0; nt < 16; ++nt) oacc[nt] *= sf;
    }
    float p[16];
    float ls = 0.0f;
    #pragma unroll
    for (int nt = 0; nt < 4; ++nt)
      #pragma unroll
      for (int r = 0; r < 4; ++r) {
        float e = __expf(sacc[nt][r] - mrow);
        p[nt * 4 + r] = e;
        ls += e;
      }
    lsum += ls;                                   // per-lane partial sum
    // ---- P -> bf16 B-frags (lane-local; k-map g*4+(e&3)+16*(e>>2)) ----
    bfrag_t pb0, pb1;
    #pragma unroll
    for (int e = 0; e < 8; ++e) { pb0[e] = f2bf(p[e]); pb1[e] = f2bf(p[8 + e]); }
    // ---- O^T += V^T P^T ----
    const char* Vbase = (const char*)&Vl[buf][0];
    __builtin_amdgcn_s_setprio(1);
    #pragma unroll
    for (int c = 0; c < 2; ++c) {
      bfrag_t pb = c ? pb1 : pb0;
      #pragma unroll
      for (int nt = 0; nt < 16; ++nt) {
        int d = nt * 16 + lrow;
        const char* vb = Vbase + d * 128;
        int o1 = (c * 64 + kch * 8) ^ sw;
        i2_t va = *reinterpret_cast<const i2_t*>(vb + o1);
        i2_t vc = *reinterpret_cast<const i2_t*>(vb + (o1 ^ 32));
        i4_t w; w.x = va.x; w.y = va.y; w.z = vc.x; w.w = vc.y;
        oacc[nt] = mfma16(__builtin_bit_cast(bfrag_t, w), pb, oacc[nt]);
      }
    }
    __builtin_amdgcn_s_setprio(0);
    asm volatile("s_waitcnt vmcnt(0)" ::: "memory");  // prefetch landed
    __syncthreads();
    buf ^= 1;
  }

  // ---- epilogue: finish l across kch groups, normalize, store ----
  lsum += __shfl_xor(lsum, 16);
  lsum += __shfl_xor(lsum, 32);
  float inv = 1.0f / lsum;
  float* Og = Out + ((size_t)b * S_ + q0 + lrow) * D_;
  #pragma unroll
  for (int nt = 0; nt < 16; ++nt) {
    float4 o;
    o.x = oacc[nt][0] * inv; o.y = oacc[nt][1] * inv;
    o.z = oacc[nt][2] * inv; o.w = oacc[nt][3] * inv;
    *reinterpret_cast<float4*>(Og + nt * 16 + kch * 4) = o;
  }
}

extern "C" void kernel_launch(void* const* d_in, const int* in_sizes, int n_in,
                              void* d_out, int out_size, void* d_ws, size_t ws_size,
                              hipStream_t stream) {
  const float* X  = (const float*)d_in[0];
  const float* Wq = (const float*)d_in[1];
  const float* Wk = (const float*)d_in[2];
  const float* Wv = (const float*)d_in[3];
  float* out = (float*)d_out;

  char* ws = (char*)d_ws;
  short* Qb = (short*)(ws);                       // 8 MB
  short* Kb = (short*)(ws + 8388608);             // 8 MB
  short* VT = (short*)(ws + 16777216);            // 8 MB (V transposed [B][D][S])
  short* WT = (short*)(ws + 25165824);            // 384 KB

  wt_kernel<<<48, 256, 0, stream>>>(Wq, Wk, Wv, WT);
  proj_kernel<<<768, 256, 0, stream>>>(X, WT, Qb, Kb, VT);
  attn_kernel<<<256, 256, 0, stream>>>(Qb, Kb, VT, out);
}

// Round 7
// 249.302 us; speedup vs baseline: 1.2824x; 1.0095x over previous
//
#include <hip/hip_runtime.h>
#include <hip/hip_bf16.h>

typedef __attribute__((ext_vector_type(8))) short bfrag_t;
typedef __attribute__((ext_vector_type(4))) float facc_t;
typedef __attribute__((ext_vector_type(2))) int i2_t;
typedef __attribute__((ext_vector_type(4))) int i4_t;

#define B_ 4
#define S_ 4096
#define D_ 256

using gas_v = const __attribute__((address_space(1))) void;
using las_v = __attribute__((address_space(3))) void;

__device__ __forceinline__ short f2bf(float f) {
  union { float fv; unsigned u; } x; x.fv = f;
  unsigned r = x.u + 0x7FFFu + ((x.u >> 16) & 1u);
  return (short)(r >> 16);
}

__device__ __forceinline__ facc_t mfma16(bfrag_t a, bfrag_t b, facc_t c) {
  return __builtin_amdgcn_mfma_f32_16x16x32_bf16(a, b, c, 0, 0, 0);
}

// ---- transpose weights to bf16: WT[p][e][d] = W_p[d][e] --------------------
__global__ void wt_kernel(const float* __restrict__ Wq, const float* __restrict__ Wk,
                          const float* __restrict__ Wv, short* __restrict__ WT) {
  const int p = blockIdx.x >> 4;
  const float* W = (p == 0) ? Wq : ((p == 1) ? Wk : Wv);
  short* o = WT + p * (D_ * D_);
  const int e = (blockIdx.x & 15) * 16 + (threadIdx.x >> 4);
  const int td = threadIdx.x & 15;
  #pragma unroll
  for (int dd = 0; dd < 16; ++dd) {
    int d = td * 16 + dd;
    o[e * D_ + d] = f2bf(W[d * D_ + e]);
  }
}

// ---- QKV projection: one projection per block (p = bid>>8) -----------------
__global__ __launch_bounds__(256) void proj_kernel(
    const float* __restrict__ X, const short* __restrict__ WT,
    short* __restrict__ Qb, short* __restrict__ Kb, short* __restrict__ VT) {
  __shared__ __align__(16) short Vt[256 * 72];    // V transpose buffer
  const int tid  = threadIdx.x;
  const int wave = tid >> 6, lane = tid & 63;
  const int lrow = lane & 15, kch = lane >> 4;
  const int p  = blockIdx.x >> 8;
  const int rb = blockIdx.x & 255;
  const int row0 = rb * 64 + wave * 16;
  const int arow = row0 + lrow;
  const int bblk = rb >> 6;                       // batch index

  bfrag_t af[8];
  #pragma unroll
  for (int kt = 0; kt < 8; ++kt) {
    const float* src = X + (size_t)arow * D_ + kt * 32 + kch * 8;
    float4 a = *reinterpret_cast<const float4*>(src);
    float4 b = *reinterpret_cast<const float4*>(src + 4);
    bfrag_t f;
    f[0] = f2bf(a.x); f[1] = f2bf(a.y); f[2] = f2bf(a.z); f[3] = f2bf(a.w);
    f[4] = f2bf(b.x); f[5] = f2bf(b.y); f[6] = f2bf(b.z); f[7] = f2bf(b.w);
    af[kt] = f;
  }

  const short* Wp = WT + p * (D_ * D_);
  facc_t acc[16];
  #pragma unroll
  for (int nt = 0; nt < 16; ++nt) acc[nt] = (facc_t)0.0f;
  #pragma unroll
  for (int kt = 0; kt < 8; ++kt) {
    #pragma unroll
    for (int nt = 0; nt < 16; ++nt) {
      bfrag_t bf = *reinterpret_cast<const bfrag_t*>(
          Wp + (nt * 16 + lrow) * D_ + kt * 32 + kch * 8);
      acc[nt] = mfma16(af[kt], bf, acc[nt]);
    }
  }
  if (p == 0) {
    #pragma unroll
    for (int nt = 0; nt < 16; ++nt)
      #pragma unroll
      for (int r = 0; r < 4; ++r)
        Qb[(size_t)(row0 + kch * 4 + r) * D_ + nt * 16 + lrow] =
            f2bf(acc[nt][r] * 0.0625f);   // fold 1/sqrt(256)
  } else if (p == 1) {
    #pragma unroll
    for (int nt = 0; nt < 16; ++nt)
      #pragma unroll
      for (int r = 0; r < 4; ++r)
        Kb[(size_t)(row0 + kch * 4 + r) * D_ + nt * 16 + lrow] = f2bf(acc[nt][r]);
  } else {
    #pragma unroll
    for (int nt = 0; nt < 16; ++nt)
      #pragma unroll
      for (int r = 0; r < 4; ++r)
        Vt[(nt * 16 + lrow) * 72 + wave * 16 + kch * 4 + r] = f2bf(acc[nt][r]);
    __syncthreads();
    const int d = tid;
    const int s0 = (rb & 63) * 64;
    short* dst = VT + ((size_t)(bblk * D_ + d)) * S_ + s0;
    #pragma unroll
    for (int j = 0; j < 8; ++j)
      *reinterpret_cast<bfrag_t*>(dst + j * 8) =
          *reinterpret_cast<const bfrag_t*>(&Vt[d * 72 + j * 8]);
  }
}

// ---- flash attention, kv-split x2 across blocks, KVB=32, 2 blocks/CU -------
// grid 512: XCD g=hw&7 -> (batch g>>1, half g&1); qt = hw>>3 in [0,64).
// Block sweeps kv [half*2048, half*2048+2048); writes raw O partial + (m,l).
__global__ __launch_bounds__(256, 2) void attn_split(
    const short* __restrict__ Qb, const short* __restrict__ Kb,
    const short* __restrict__ VT, float* __restrict__ P0,
    float* __restrict__ P1, float2* __restrict__ ML) {
  // K tile [32 kv][256 d] (512B rows, byte ^= (row&7)<<4)
  // V tile [256 d][32 kv] (64B rows,  byte ^= (d&3)<<4, 16B-granular)
  __shared__ __align__(16) short Kl[2][32 * 256];
  __shared__ __align__(16) short Vl[2][256 * 32];
  const int tid  = threadIdx.x;
  const int wave = tid >> 6, lane = tid & 63;
  const int lrow = lane & 15, kch = lane >> 4;
  const int ksw = (lrow & 7) << 4;
  const int vsw = (lrow & 3) << 4;
  const int hw = blockIdx.x;
  const int g = hw & 7;
  const int b = g >> 1, half = g & 1;
  const int q0 = (hw >> 3) * 64 + wave * 16;      // wave's q-rows in batch
  const int kvbase = half * 2048;

  const short* Kbp = Kb + (size_t)b * S_ * D_ + (size_t)kvbase * D_;
  const short* Vbp = VT + (size_t)b * D_ * S_ + kvbase;

  // Q as B-operand: lane holds q-col lrow, k = kt*32 + kch*8 + e
  bfrag_t qf[8];
  #pragma unroll
  for (int kt = 0; kt < 8; ++kt)
    qf[kt] = *reinterpret_cast<const bfrag_t*>(
        Qb + ((size_t)b * S_ + q0 + lrow) * D_ + kt * 32 + kch * 8);

  // stage one 32-kv tile (K 16KB + V 16KB), 8 x 16B DMA per thread
  auto stage = [&](int bf, int kv0) {
    #pragma unroll
    for (int j = 0; j < 4; ++j) {
      int L = j * 4096 + tid * 16;
      int row = L >> 9;
      int cs = (L & 511) ^ ((row & 7) << 4);
      const short* src = Kbp + (size_t)(kv0 + row) * D_ + (cs >> 1);
      short* dst = &Kl[bf][(j * 4096 + wave * 1024) >> 1];
      __builtin_amdgcn_global_load_lds((gas_v*)src, (las_v*)dst, 16, 0, 0);
    }
    #pragma unroll
    for (int j = 0; j < 4; ++j) {
      int L = j * 4096 + tid * 16;
      int d = L >> 6;
      int cs = (L & 63) ^ ((d & 3) << 4);
      const short* src = Vbp + (size_t)d * S_ + kv0 + (cs >> 1);
      short* dst = &Vl[bf][(j * 4096 + wave * 1024) >> 1];
      __builtin_amdgcn_global_load_lds((gas_v*)src, (las_v*)dst, 16, 0, 0);
    }
  };

  facc_t oacc[16];
  #pragma unroll
  for (int nt = 0; nt < 16; ++nt) oacc[nt] = (facc_t)0.0f;
  float mrow = -3.0e38f, lsum = 0.0f;

  stage(0, 0);
  asm volatile("s_waitcnt vmcnt(0)" ::: "memory");
  __syncthreads();
  int buf = 0;

  #pragma unroll 1
  for (int t = 0; t < 64; ++t) {
    if (t < 63) stage(buf ^ 1, (t + 1) * 32);     // issue-early prefetch
    // ---- S^T = K Q^T : 2 kv-tiles x 8 kt ----
    facc_t sacc[2];
    sacc[0] = (facc_t)0.0f; sacc[1] = (facc_t)0.0f;
    const char* Kbase = (const char*)&Kl[buf][0];
    __builtin_amdgcn_s_setprio(1);
    #pragma unroll
    for (int kt = 0; kt < 8; ++kt) {
      #pragma unroll
      for (int nt = 0; nt < 2; ++nt) {
        int row = nt * 16 + lrow;
        bfrag_t kf = *reinterpret_cast<const bfrag_t*>(
            Kbase + row * 512 + ((kt * 64 + kch * 16) ^ ksw));
        sacc[nt] = mfma16(kf, qf[kt], sacc[nt]);
      }
    }
    __builtin_amdgcn_s_setprio(0);
    // ---- softmax: lane owns q-row lrow, 8 kv values; 2 shfls ----
    float mx = fmaxf(fmaxf(sacc[0][0], sacc[0][1]), fmaxf(sacc[0][2], sacc[0][3]));
    mx = fmaxf(mx, fmaxf(fmaxf(sacc[1][0], sacc[1][1]),
                         fmaxf(sacc[1][2], sacc[1][3])));
    mx = fmaxf(mx, __shfl_xor(mx, 16));
    mx = fmaxf(mx, __shfl_xor(mx, 32));
    if (mx > mrow + 8.0f) {                       // defer-max rescale
      float sf = __expf(mrow - mx);
      mrow = mx;
      lsum *= sf;
      #pragma unroll
      for (int nt = 0; nt < 16; ++nt) oacc[nt] *= sf;
    }
    float p[8];
    float ls = 0.0f;
    #pragma unroll
    for (int nt = 0; nt < 2; ++nt)
      #pragma unroll
      for (int r = 0; r < 4; ++r) {
        float e = __expf(sacc[nt][r] - mrow);
        p[nt * 4 + r] = e;
        ls += e;
      }
    lsum += ls;                                   // per-lane partial sum
    // ---- P -> bf16 B-frag (lane-local; k-map kv = 4*kch+(e&3)+16*(e>>2)) --
    bfrag_t pb;
    #pragma unroll
    for (int e = 0; e < 8; ++e) pb[e] = f2bf(p[e]);
    // ---- O^T += V^T P^T ----
    const char* Vbase = (const char*)&Vl[buf][0];
    __builtin_amdgcn_s_setprio(1);
    #pragma unroll
    for (int nt = 0; nt < 16; ++nt) {
      int d = nt * 16 + lrow;
      const char* vb = Vbase + d * 64;
      int o1 = (kch * 8) ^ vsw;
      i2_t va = *reinterpret_cast<const i2_t*>(vb + o1);
      i2_t vc = *reinterpret_cast<const i2_t*>(vb + (o1 ^ 32));
      i4_t w; w.x = va.x; w.y = va.y; w.z = vc.x; w.w = vc.y;
      oacc[nt] = mfma16(__builtin_bit_cast(bfrag_t, w), pb, oacc[nt]);
    }
    __builtin_amdgcn_s_setprio(0);
    asm volatile("s_waitcnt vmcnt(0)" ::: "memory");  // prefetch landed
    __syncthreads();
    buf ^= 1;
  }

  // ---- epilogue: reduce l across kch groups, store raw partial + (m,l) ----
  lsum += __shfl_xor(lsum, 16);
  lsum += __shfl_xor(lsum, 32);
  float* Pd = half ? P1 : P0;
  float* Og = Pd + ((size_t)b * S_ + q0 + lrow) * D_;
  #pragma unroll
  for (int nt = 0; nt < 16; ++nt) {
    float4 o;
    o.x = oacc[nt][0]; o.y = oacc[nt][1];
    o.z = oacc[nt][2]; o.w = oacc[nt][3];
    *reinterpret_cast<float4*>(Og + nt * 16 + kch * 4) = o;
  }
  if (lane < 16) {
    float2 ml; ml.x = mrow; ml.y = lsum;
    ML[half * (B_ * S_) + b * S_ + q0 + lrow] = ml;
  }
}

// ---- combine two kv-half partials ------------------------------------------
__global__ __launch_bounds__(256) void combine_kernel(
    const float* __restrict__ P1, const float2* __restrict__ ML,
    float* __restrict__ Out) {
  const int r = blockIdx.x * 4 + (threadIdx.x >> 6);
  const int d4 = (threadIdx.x & 63) * 4;
  float2 a0 = ML[r], a1 = ML[B_ * S_ + r];
  float m = fmaxf(a0.x, a1.x);
  float w0 = __expf(a0.x - m), w1 = __expf(a1.x - m);
  float inv = 1.0f / (a0.y * w0 + a1.y * w1);
  w0 *= inv; w1 *= inv;
  size_t idx = (size_t)r * D_ + d4;
  float4 x = *reinterpret_cast<float4*>(Out + idx);
  float4 y = *reinterpret_cast<const float4*>(P1 + idx);
  x.x = x.x * w0 + y.x * w1;
  x.y = x.y * w0 + y.y * w1;
  x.z = x.z * w0 + y.z * w1;
  x.w = x.w * w0 + y.w * w1;
  *reinterpret_cast<float4*>(Out + idx) = x;
}

// ---- fallback: round-6 single-pass attention (if ws too small) -------------
__global__ __launch_bounds__(256, 1) void attn_full(
    const short* __restrict__ Qb, const short* __restrict__ Kb,
    const short* __restrict__ VT, float* __restrict__ Out) {
  __shared__ __align__(16) short Kl[2][64 * 256];
  __shared__ __align__(16) short Vl[2][256 * 64];
  const int tid  = threadIdx.x;
  const int wave = tid >> 6, lane = tid & 63;
  const int lrow = lane & 15, kch = lane >> 4;
  const int sw = (lrow & 7) << 4;
  const int bid = ((blockIdx.x & 7) << 5) | (blockIdx.x >> 3);
  const int b  = bid >> 6;
  const int q0 = (bid & 63) * 64 + wave * 16;

  const short* Kbp = Kb + (size_t)b * S_ * D_;
  const short* Vbp = VT + (size_t)b * D_ * S_;

  bfrag_t qf[8];
  #pragma unroll
  for (int kt = 0; kt < 8; ++kt)
    qf[kt] = *reinterpret_cast<const bfrag_t*>(
        Qb + ((size_t)b * S_ + q0 + lrow) * D_ + kt * 32 + kch * 8);

  auto stage = [&](int bf, int kv0) {
    #pragma unroll
    for (int j = 0; j < 8; ++j) {
      int L = j * 4096 + tid * 16;
      int row = L >> 9;
      int cs = (L & 511) ^ ((row & 7) << 4);
      const short* src = Kbp + (size_t)(kv0 + row) * D_ + (cs >> 1);
      short* dst = &Kl[bf][(j * 4096 + wave * 1024) >> 1];
      __builtin_amdgcn_global_load_lds((gas_v*)src, (las_v*)dst, 16, 0, 0);
    }
    #pragma unroll
    for (int j = 0; j < 8; ++j) {
      int L = j * 4096 + tid * 16;
      int d = L >> 7;
      int cs = (L & 127) ^ ((d & 7) << 4);
      const short* src = Vbp + (size_t)d * S_ + kv0 + (cs >> 1);
      short* dst = &Vl[bf][(j * 4096 + wave * 1024) >> 1];
      __builtin_amdgcn_global_load_lds((gas_v*)src, (las_v*)dst, 16, 0, 0);
    }
  };

  facc_t oacc[16];
  #pragma unroll
  for (int nt = 0; nt < 16; ++nt) oacc[nt] = (facc_t)0.0f;
  float mrow = -3.0e38f, lsum = 0.0f;

  stage(0, 0);
  asm volatile("s_waitcnt vmcnt(0)" ::: "memory");
  __syncthreads();
  int buf = 0;

  #pragma unroll 1
  for (int t = 0; t < 64; ++t) {
    if (t < 63) stage(buf ^ 1, (t + 1) * 64);
    facc_t sacc[4];
    #pragma unroll
    for (int nt = 0; nt < 4; ++nt) sacc[nt] = (facc_t)0.0f;
    const char* Kbase = (const char*)&Kl[buf][0];
    __builtin_amdgcn_s_setprio(1);
    #pragma unroll
    for (int kt = 0; kt < 8; ++kt) {
      #pragma unroll
      for (int nt = 0; nt < 4; ++nt) {
        int row = nt * 16 + lrow;
        bfrag_t kf = *reinterpret_cast<const bfrag_t*>(
            Kbase + row * 512 + ((kt * 64 + kch * 16) ^ sw));
        sacc[nt] = mfma16(kf, qf[kt], sacc[nt]);
      }
    }
    __builtin_amdgcn_s_setprio(0);
    float mx = fmaxf(fmaxf(sacc[0][0], sacc[0][1]), fmaxf(sacc[0][2], sacc[0][3]));
    #pragma unroll
    for (int nt = 1; nt < 4; ++nt)
      mx = fmaxf(mx, fmaxf(fmaxf(sacc[nt][0], sacc[nt][1]),
                           fmaxf(sacc[nt][2], sacc[nt][3])));
    mx = fmaxf(mx, __shfl_xor(mx, 16));
    mx = fmaxf(mx, __shfl_xor(mx, 32));
    if (mx > mrow + 8.0f) {
      float sf = __expf(mrow - mx);
      mrow = mx;
      lsum *= sf;
      #pragma unroll
      for (int nt = 0; nt < 16; ++nt) oacc[nt] *= sf;
    }
    float p[16];
    float ls = 0.0f;
    #pragma unroll
    for (int nt = 0; nt < 4; ++nt)
      #pragma unroll
      for (int r = 0; r < 4; ++r) {
        float e = __expf(sacc[nt][r] - mrow);
        p[nt * 4 + r] = e;
        ls += e;
      }
    lsum += ls;
    bfrag_t pb0, pb1;
    #pragma unroll
    for (int e = 0; e < 8; ++e) { pb0[e] = f2bf(p[e]); pb1[e] = f2bf(p[8 + e]); }
    const char* Vbase = (const char*)&Vl[buf][0];
    __builtin_amdgcn_s_setprio(1);
    #pragma unroll
    for (int c = 0; c < 2; ++c) {
      bfrag_t pb = c ? pb1 : pb0;
      #pragma unroll
      for (int nt = 0; nt < 16; ++nt) {
        int d = nt * 16 + lrow;
        const char* vb = Vbase + d * 128;
        int o1 = (c * 64 + kch * 8) ^ sw;
        i2_t va = *reinterpret_cast<const i2_t*>(vb + o1);
        i2_t vc = *reinterpret_cast<const i2_t*>(vb + (o1 ^ 32));
        i4_t w; w.x = va.x; w.y = va.y; w.z = vc.x; w.w = vc.y;
        oacc[nt] = mfma16(__builtin_bit_cast(bfrag_t, w), pb, oacc[nt]);
      }
    }
    __builtin_amdgcn_s_setprio(0);
    asm volatile("s_waitcnt vmcnt(0)" ::: "memory");
    __syncthreads();
    buf ^= 1;
  }

  lsum += __shfl_xor(lsum, 16);
  lsum += __shfl_xor(lsum, 32);
  float inv = 1.0f / lsum;
  float* Og = Out + ((size_t)b * S_ + q0 + lrow) * D_;
  #pragma unroll
  for (int nt = 0; nt < 16; ++nt) {
    float4 o;
    o.x = oacc[nt][0] * inv; o.y = oacc[nt][1] * inv;
    o.z = oacc[nt][2] * inv; o.w = oacc[nt][3] * inv;
    *reinterpret_cast<float4*>(Og + nt * 16 + kch * 4) = o;
  }
}

extern "C" void kernel_launch(void* const* d_in, const int* in_sizes, int n_in,
                              void* d_out, int out_size, void* d_ws, size_t ws_size,
                              hipStream_t stream) {
  const float* X  = (const float*)d_in[0];
  const float* Wq = (const float*)d_in[1];
  const float* Wk = (const float*)d_in[2];
  const float* Wv = (const float*)d_in[3];
  float* out = (float*)d_out;

  char* ws = (char*)d_ws;
  short* Qb = (short*)(ws);                       // 8 MB
  short* Kb = (short*)(ws + 8388608);             // 8 MB
  short* VT = (short*)(ws + 16777216);            // 8 MB (V transposed [B][D][S])
  short* WT = (short*)(ws + 25165824);            // 384 KB
  float2* ML = (float2*)(ws + 25559040);          // 256 KB (m,l for both halves)
  float* P1  = (float*)(ws + 25821184);           // 16 MB (kv-half-1 partial)
  const size_t need = 25821184 + (size_t)B_ * S_ * D_ * 4;

  wt_kernel<<<48, 256, 0, stream>>>(Wq, Wk, Wv, WT);
  proj_kernel<<<768, 256, 0, stream>>>(X, WT, Qb, Kb, VT);
  if (ws_size >= need) {
    attn_split<<<512, 256, 0, stream>>>(Qb, Kb, VT, out, P1, ML);
    combine_kernel<<<(B_ * S_) / 4, 256, 0, stream>>>(P1, ML, out);
  } else {
    attn_full<<<256, 256, 0, stream>>>(Qb, Kb, VT, out);
  }
}

// Round 8
// 177.503 us; speedup vs baseline: 1.8011x; 1.4045x over previous
//
#include <hip/hip_runtime.h>
#include <hip/hip_bf16.h>

typedef __attribute__((ext_vector_type(8))) short bfrag_t;
typedef __attribute__((ext_vector_type(4))) float facc_t;

#define B_ 4
#define S_ 4096
#define D_ 256

using gas_v = const __attribute__((address_space(1))) void;
using las_v = __attribute__((address_space(3))) void;

__device__ __forceinline__ short f2bf(float f) {
  union { float fv; unsigned u; } x; x.fv = f;
  unsigned r = x.u + 0x7FFFu + ((x.u >> 16) & 1u);
  return (short)(r >> 16);
}

__device__ __forceinline__ facc_t mfma16(bfrag_t a, bfrag_t b, facc_t c) {
  return __builtin_amdgcn_mfma_f32_16x16x32_bf16(a, b, c, 0, 0, 0);
}

// ---- transpose weights to bf16: WT[p][e][d] = W_p[d][e] --------------------
__global__ void wt_kernel(const float* __restrict__ Wq, const float* __restrict__ Wk,
                          const float* __restrict__ Wv, short* __restrict__ WT) {
  const int p = blockIdx.x >> 4;
  const float* W = (p == 0) ? Wq : ((p == 1) ? Wk : Wv);
  short* o = WT + p * (D_ * D_);
  const int e = (blockIdx.x & 15) * 16 + (threadIdx.x >> 4);
  const int td = threadIdx.x & 15;
  #pragma unroll
  for (int dd = 0; dd < 16; ++dd) {
    int d = td * 16 + dd;
    o[e * D_ + d] = f2bf(W[d * D_ + e]);
  }
}

// ---- QKV projection: one projection per block (p = bid>>8) -----------------
// V is stored TRANSPOSED and slot-PERMUTED within each 32-kv tile:
//   slot(kv) = (kv&3) + 4*((kv>>4)&1) + 8*((kv>>2)&3)
// so PV A-frags are single contiguous b128 reads in the attention kernel.
__global__ __launch_bounds__(256) void proj_kernel(
    const float* __restrict__ X, const short* __restrict__ WT,
    short* __restrict__ Qb, short* __restrict__ Kb, short* __restrict__ VT) {
  __shared__ __align__(16) short Vt[256 * 72];    // V transpose buffer
  const int tid  = threadIdx.x;
  const int wave = tid >> 6, lane = tid & 63;
  const int lrow = lane & 15, kch = lane >> 4;
  const int p  = blockIdx.x >> 8;
  const int rb = blockIdx.x & 255;
  const int row0 = rb * 64 + wave * 16;
  const int arow = row0 + lrow;
  const int bblk = rb >> 6;                       // batch index

  bfrag_t af[8];
  #pragma unroll
  for (int kt = 0; kt < 8; ++kt) {
    const float* src = X + (size_t)arow * D_ + kt * 32 + kch * 8;
    float4 a = *reinterpret_cast<const float4*>(src);
    float4 b = *reinterpret_cast<const float4*>(src + 4);
    bfrag_t f;
    f[0] = f2bf(a.x); f[1] = f2bf(a.y); f[2] = f2bf(a.z); f[3] = f2bf(a.w);
    f[4] = f2bf(b.x); f[5] = f2bf(b.y); f[6] = f2bf(b.z); f[7] = f2bf(b.w);
    af[kt] = f;
  }

  const short* Wp = WT + p * (D_ * D_);
  facc_t acc[16];
  #pragma unroll
  for (int nt = 0; nt < 16; ++nt) acc[nt] = (facc_t)0.0f;
  #pragma unroll
  for (int kt = 0; kt < 8; ++kt) {
    #pragma unroll
    for (int nt = 0; nt < 16; ++nt) {
      bfrag_t bf = *reinterpret_cast<const bfrag_t*>(
          Wp + (nt * 16 + lrow) * D_ + kt * 32 + kch * 8);
      acc[nt] = mfma16(af[kt], bf, acc[nt]);
    }
  }
  if (p == 0) {
    #pragma unroll
    for (int nt = 0; nt < 16; ++nt)
      #pragma unroll
      for (int r = 0; r < 4; ++r)
        Qb[(size_t)(row0 + kch * 4 + r) * D_ + nt * 16 + lrow] =
            f2bf(acc[nt][r] * 0.0625f);   // fold 1/sqrt(256)
  } else if (p == 1) {
    #pragma unroll
    for (int nt = 0; nt < 16; ++nt)
      #pragma unroll
      for (int r = 0; r < 4; ++r)
        Kb[(size_t)(row0 + kch * 4 + r) * D_ + nt * 16 + lrow] = f2bf(acc[nt][r]);
  } else {
    // local kv (within 64-row block) = wave*16 + kch*4 + r
    // permuted column = (wave>>1)*32 + kch*8 + (wave&1)*4 + r
    #pragma unroll
    for (int nt = 0; nt < 16; ++nt)
      #pragma unroll
      for (int r = 0; r < 4; ++r)
        Vt[(nt * 16 + lrow) * 72 + (wave >> 1) * 32 + kch * 8 + (wave & 1) * 4 + r] =
            f2bf(acc[nt][r]);
    __syncthreads();
    const int d = tid;
    const int s0 = (rb & 63) * 64;
    short* dst = VT + ((size_t)(bblk * D_ + d)) * S_ + s0;
    #pragma unroll
    for (int j = 0; j < 8; ++j)
      *reinterpret_cast<bfrag_t*>(dst + j * 8) =
          *reinterpret_cast<const bfrag_t*>(&Vt[d * 72 + j * 8]);
  }
}

// ---- flash attention, kv-split x2 across blocks, KVB=32, 2 blocks/CU -------
// grid 512: XCD g=hw&7 -> (batch g>>1, half g&1); qt = hw>>3 in [0,64).
__global__ __launch_bounds__(256, 2) void attn_split(
    const short* __restrict__ Qb, const short* __restrict__ Kb,
    const short* __restrict__ VT, float* __restrict__ P0,
    float* __restrict__ P1, float2* __restrict__ ML) {
  // K tile [32 kv][256 d] (512B rows, byte ^= (row&7)<<4)
  // V tile [256 d][32 kv-slots] (64B rows, slot-permuted, NO swizzle needed)
  __shared__ __align__(16) short Kl[2][32 * 256];
  __shared__ __align__(16) short Vl[2][256 * 32];
  const int tid  = threadIdx.x;
  const int wave = tid >> 6, lane = tid & 63;
  const int lrow = lane & 15, kch = lane >> 4;
  const int ksw = (lrow & 7) << 4;
  const int hw = blockIdx.x;
  const int g = hw & 7;
  const int b = g >> 1, half = g & 1;
  const int q0 = (hw >> 3) * 64 + wave * 16;      // wave's q-rows in batch
  const int kvbase = half * 2048;

  const short* Kbp = Kb + (size_t)b * S_ * D_ + (size_t)kvbase * D_;
  const short* Vbp = VT + (size_t)b * D_ * S_ + kvbase;

  // Q as B-operand: lane holds q-col lrow, k = kt*32 + kch*8 + e
  bfrag_t qf[8];
  #pragma unroll
  for (int kt = 0; kt < 8; ++kt)
    qf[kt] = *reinterpret_cast<const bfrag_t*>(
        Qb + ((size_t)b * S_ + q0 + lrow) * D_ + kt * 32 + kch * 8);

  // stage one 32-kv tile (K 16KB + V 16KB), 8 x 16B DMA per thread
  auto stage = [&](int bf, int kv0) {
    #pragma unroll
    for (int j = 0; j < 4; ++j) {
      int L = j * 4096 + tid * 16;
      int row = L >> 9;
      int cs = (L & 511) ^ ((row & 7) << 4);      // inverse-swizzled source
      const short* src = Kbp + (size_t)(kv0 + row) * D_ + (cs >> 1);
      short* dst = &Kl[bf][(j * 4096 + wave * 1024) >> 1];
      __builtin_amdgcn_global_load_lds((gas_v*)src, (las_v*)dst, 16, 0, 0);
    }
    #pragma unroll
    for (int j = 0; j < 4; ++j) {
      int L = j * 4096 + tid * 16;
      int d = L >> 6;
      const short* src = Vbp + (size_t)d * S_ + kv0 + ((L & 63) >> 1);
      short* dst = &Vl[bf][(j * 4096 + wave * 1024) >> 1];
      __builtin_amdgcn_global_load_lds((gas_v*)src, (las_v*)dst, 16, 0, 0);
    }
  };

  facc_t oacc[16];
  #pragma unroll
  for (int nt = 0; nt < 16; ++nt) oacc[nt] = (facc_t)0.0f;
  float mrow = -3.0e38f, lsum = 0.0f;

  stage(0, 0);
  asm volatile("s_waitcnt vmcnt(0)" ::: "memory");
  __syncthreads();
  int buf = 0;

  #pragma unroll 1
  for (int t = 0; t < 64; ++t) {
    if (t < 63) stage(buf ^ 1, (t + 1) * 32);     // issue-early prefetch
    // ---- S^T = K Q^T : 2 kv-tiles x 8 kt ----
    facc_t sacc[2];
    sacc[0] = (facc_t)0.0f; sacc[1] = (facc_t)0.0f;
    const char* Kbase = (const char*)&Kl[buf][0];
    __builtin_amdgcn_s_setprio(1);
    #pragma unroll
    for (int kt = 0; kt < 8; ++kt) {
      #pragma unroll
      for (int nt = 0; nt < 2; ++nt) {
        int row = nt * 16 + lrow;
        bfrag_t kf = *reinterpret_cast<const bfrag_t*>(
            Kbase + row * 512 + ((kt * 64 + kch * 16) ^ ksw));
        sacc[nt] = mfma16(kf, qf[kt], sacc[nt]);
      }
    }
    __builtin_amdgcn_s_setprio(0);
    // ---- softmax: lane owns q-row lrow, 8 kv values; 2 shfls ----
    float mx = fmaxf(fmaxf(sacc[0][0], sacc[0][1]), fmaxf(sacc[0][2], sacc[0][3]));
    mx = fmaxf(mx, fmaxf(fmaxf(sacc[1][0], sacc[1][1]),
                         fmaxf(sacc[1][2], sacc[1][3])));
    mx = fmaxf(mx, __shfl_xor(mx, 16));
    mx = fmaxf(mx, __shfl_xor(mx, 32));
    if (mx > mrow + 8.0f) {                       // defer-max rescale
      float sf = __expf(mrow - mx);
      mrow = mx;
      lsum *= sf;
      #pragma unroll
      for (int nt = 0; nt < 16; ++nt) oacc[nt] *= sf;
    }
    float p[8];
    float ls = 0.0f;
    #pragma unroll
    for (int nt = 0; nt < 2; ++nt)
      #pragma unroll
      for (int r = 0; r < 4; ++r) {
        float e = __expf(sacc[nt][r] - mrow);
        p[nt * 4 + r] = e;
        ls += e;
      }
    lsum += ls;                                   // per-lane partial sum
    // ---- P -> bf16 B-frag (lane-local; k-map kv = 4*kch+(e&3)+16*(e>>2)) --
    bfrag_t pb;
    #pragma unroll
    for (int e = 0; e < 8; ++e) pb[e] = f2bf(p[e]);
    // ---- O^T += V^T P^T : V A-frag is ONE b128 (permuted layout) ----
    const char* Vbase = (const char*)&Vl[buf][0];
    __builtin_amdgcn_s_setprio(1);
    #pragma unroll
    for (int nt = 0; nt < 16; ++nt) {
      int d = nt * 16 + lrow;
      bfrag_t vf = *reinterpret_cast<const bfrag_t*>(Vbase + d * 64 + kch * 16);
      oacc[nt] = mfma16(vf, pb, oacc[nt]);
    }
    __builtin_amdgcn_s_setprio(0);
    asm volatile("s_waitcnt vmcnt(0)" ::: "memory");  // prefetch landed
    __syncthreads();
    buf ^= 1;
  }

  // ---- epilogue: reduce l across kch groups, store raw partial + (m,l) ----
  lsum += __shfl_xor(lsum, 16);
  lsum += __shfl_xor(lsum, 32);
  float* Pd = half ? P1 : P0;
  float* Og = Pd + ((size_t)b * S_ + q0 + lrow) * D_;
  #pragma unroll
  for (int nt = 0; nt < 16; ++nt) {
    float4 o;
    o.x = oacc[nt][0]; o.y = oacc[nt][1];
    o.z = oacc[nt][2]; o.w = oacc[nt][3];
    *reinterpret_cast<float4*>(Og + nt * 16 + kch * 4) = o;
  }
  if (lane < 16) {
    float2 ml; ml.x = mrow; ml.y = lsum;
    ML[half * (B_ * S_) + b * S_ + q0 + lrow] = ml;
  }
}

// ---- combine two kv-half partials ------------------------------------------
__global__ __launch_bounds__(256) void combine_kernel(
    const float* __restrict__ P1, const float2* __restrict__ ML,
    float* __restrict__ Out) {
  const int r = blockIdx.x * 4 + (threadIdx.x >> 6);
  const int d4 = (threadIdx.x & 63) * 4;
  float2 a0 = ML[r], a1 = ML[B_ * S_ + r];
  float m = fmaxf(a0.x, a1.x);
  float w0 = __expf(a0.x - m), w1 = __expf(a1.x - m);
  float inv = 1.0f / (a0.y * w0 + a1.y * w1);
  w0 *= inv; w1 *= inv;
  size_t idx = (size_t)r * D_ + d4;
  float4 x = *reinterpret_cast<float4*>(Out + idx);
  float4 y = *reinterpret_cast<const float4*>(P1 + idx);
  x.x = x.x * w0 + y.x * w1;
  x.y = x.y * w0 + y.y * w1;
  x.z = x.z * w0 + y.z * w1;
  x.w = x.w * w0 + y.w * w1;
  *reinterpret_cast<float4*>(Out + idx) = x;
}

// ---- fallback: single-pass attention (updated for permuted V layout) -------
__global__ __launch_bounds__(256, 1) void attn_full(
    const short* __restrict__ Qb, const short* __restrict__ Kb,
    const short* __restrict__ VT, float* __restrict__ Out) {
  __shared__ __align__(16) short Kl[2][64 * 256];
  __shared__ __align__(16) short Vl[2][256 * 64];
  const int tid  = threadIdx.x;
  const int wave = tid >> 6, lane = tid & 63;
  const int lrow = lane & 15, kch = lane >> 4;
  const int sw = (lrow & 7) << 4;
  const int bid = ((blockIdx.x & 7) << 5) | (blockIdx.x >> 3);
  const int b  = bid >> 6;
  const int q0 = (bid & 63) * 64 + wave * 16;

  const short* Kbp = Kb + (size_t)b * S_ * D_;
  const short* Vbp = VT + (size_t)b * D_ * S_;

  bfrag_t qf[8];
  #pragma unroll
  for (int kt = 0; kt < 8; ++kt)
    qf[kt] = *reinterpret_cast<const bfrag_t*>(
        Qb + ((size_t)b * S_ + q0 + lrow) * D_ + kt * 32 + kch * 8);

  auto stage = [&](int bf, int kv0) {
    #pragma unroll
    for (int j = 0; j < 8; ++j) {
      int L = j * 4096 + tid * 16;
      int row = L >> 9;
      int cs = (L & 511) ^ ((row & 7) << 4);
      const short* src = Kbp + (size_t)(kv0 + row) * D_ + (cs >> 1);
      short* dst = &Kl[bf][(j * 4096 + wave * 1024) >> 1];
      __builtin_amdgcn_global_load_lds((gas_v*)src, (las_v*)dst, 16, 0, 0);
    }
    #pragma unroll
    for (int j = 0; j < 8; ++j) {
      int L = j * 4096 + tid * 16;
      int d = L >> 7;
      int cs = (L & 127) ^ ((d & 7) << 4);
      const short* src = Vbp + (size_t)d * S_ + kv0 + (cs >> 1);
      short* dst = &Vl[bf][(j * 4096 + wave * 1024) >> 1];
      __builtin_amdgcn_global_load_lds((gas_v*)src, (las_v*)dst, 16, 0, 0);
    }
  };

  facc_t oacc[16];
  #pragma unroll
  for (int nt = 0; nt < 16; ++nt) oacc[nt] = (facc_t)0.0f;
  float mrow = -3.0e38f, lsum = 0.0f;

  stage(0, 0);
  asm volatile("s_waitcnt vmcnt(0)" ::: "memory");
  __syncthreads();
  int buf = 0;

  #pragma unroll 1
  for (int t = 0; t < 64; ++t) {
    if (t < 63) stage(buf ^ 1, (t + 1) * 64);
    facc_t sacc[4];
    #pragma unroll
    for (int nt = 0; nt < 4; ++nt) sacc[nt] = (facc_t)0.0f;
    const char* Kbase = (const char*)&Kl[buf][0];
    __builtin_amdgcn_s_setprio(1);
    #pragma unroll
    for (int kt = 0; kt < 8; ++kt) {
      #pragma unroll
      for (int nt = 0; nt < 4; ++nt) {
        int row = nt * 16 + lrow;
        bfrag_t kf = *reinterpret_cast<const bfrag_t*>(
            Kbase + row * 512 + ((kt * 64 + kch * 16) ^ sw));
        sacc[nt] = mfma16(kf, qf[kt], sacc[nt]);
      }
    }
    __builtin_amdgcn_s_setprio(0);
    float mx = fmaxf(fmaxf(sacc[0][0], sacc[0][1]), fmaxf(sacc[0][2], sacc[0][3]));
    #pragma unroll
    for (int nt = 1; nt < 4; ++nt)
      mx = fmaxf(mx, fmaxf(fmaxf(sacc[nt][0], sacc[nt][1]),
                           fmaxf(sacc[nt][2], sacc[nt][3])));
    mx = fmaxf(mx, __shfl_xor(mx, 16));
    mx = fmaxf(mx, __shfl_xor(mx, 32));
    if (mx > mrow + 8.0f) {
      float sf = __expf(mrow - mx);
      mrow = mx;
      lsum *= sf;
      #pragma unroll
      for (int nt = 0; nt < 16; ++nt) oacc[nt] *= sf;
    }
    float p[16];
    float ls = 0.0f;
    #pragma unroll
    for (int nt = 0; nt < 4; ++nt)
      #pragma unroll
      for (int r = 0; r < 4; ++r) {
        float e = __expf(sacc[nt][r] - mrow);
        p[nt * 4 + r] = e;
        ls += e;
      }
    lsum += ls;
    bfrag_t pb0, pb1;
    #pragma unroll
    for (int e = 0; e < 8; ++e) { pb0[e] = f2bf(p[e]); pb1[e] = f2bf(p[8 + e]); }
    const char* Vbase = (const char*)&Vl[buf][0];
    __builtin_amdgcn_s_setprio(1);
    #pragma unroll
    for (int c = 0; c < 2; ++c) {
      bfrag_t pb = c ? pb1 : pb0;
      #pragma unroll
      for (int nt = 0; nt < 16; ++nt) {
        int d = nt * 16 + lrow;
        bfrag_t vf = *reinterpret_cast<const bfrag_t*>(
            Vbase + d * 128 + ((c * 64 + kch * 16) ^ ((d & 7) << 4)));
        oacc[nt] = mfma16(vf, pb, oacc[nt]);
      }
    }
    __builtin_amdgcn_s_setprio(0);
    asm volatile("s_waitcnt vmcnt(0)" ::: "memory");
    __syncthreads();
    buf ^= 1;
  }

  lsum += __shfl_xor(lsum, 16);
  lsum += __shfl_xor(lsum, 32);
  float inv = 1.0f / lsum;
  float* Og = Out + ((size_t)b * S_ + q0 + lrow) * D_;
  #pragma unroll
  for (int nt = 0; nt < 16; ++nt) {
    float4 o;
    o.x = oacc[nt][0] * inv; o.y = oacc[nt][1] * inv;
    o.z = oacc[nt][2] * inv; o.w = oacc[nt][3] * inv;
    *reinterpret_cast<float4*>(Og + nt * 16 + kch * 4) = o;
  }
}

extern "C" void kernel_launch(void* const* d_in, const int* in_sizes, int n_in,
                              void* d_out, int out_size, void* d_ws, size_t ws_size,
                              hipStream_t stream) {
  const float* X  = (const float*)d_in[0];
  const float* Wq = (const float*)d_in[1];
  const float* Wk = (const float*)d_in[2];
  const float* Wv = (const float*)d_in[3];
  float* out = (float*)d_out;

  char* ws = (char*)d_ws;
  short* Qb = (short*)(ws);                       // 8 MB
  short* Kb = (short*)(ws + 8388608);             // 8 MB
  short* VT = (short*)(ws + 16777216);            // 8 MB (V^T, slot-permuted)
  short* WT = (short*)(ws + 25165824);            // 384 KB
  float2* ML = (float2*)(ws + 25559040);          // 256 KB (m,l both halves)
  float* P1  = (float*)(ws + 25821184);           // 16 MB (kv-half-1 partial)
  const size_t need = 25821184 + (size_t)B_ * S_ * D_ * 4;

  wt_kernel<<<48, 256, 0, stream>>>(Wq, Wk, Wv, WT);
  proj_kernel<<<768, 256, 0, stream>>>(X, WT, Qb, Kb, VT);
  if (ws_size >= need) {
    attn_split<<<512, 256, 0, stream>>>(Qb, Kb, VT, out, P1, ML);
    combine_kernel<<<(B_ * S_) / 4, 256, 0, stream>>>(P1, ML, out);
  } else {
    attn_full<<<256, 256, 0, stream>>>(Qb, Kb, VT, out);
  }
}

// Round 9
// 160.030 us; speedup vs baseline: 1.9977x; 1.1092x over previous
//
#include <hip/hip_runtime.h>
#include <hip/hip_bf16.h>

typedef __attribute__((ext_vector_type(8))) short bfrag_t;
typedef __attribute__((ext_vector_type(4))) float facc_t;
typedef __attribute__((ext_vector_type(16))) float f16acc_t;
typedef __attribute__((ext_vector_type(4))) int i4_t;

#define B_ 4
#define S_ 4096
#define D_ 256

using gas_v = const __attribute__((address_space(1))) void;
using las_v = __attribute__((address_space(3))) void;

__device__ __forceinline__ short f2bf(float f) {
  union { float fv; unsigned u; } x; x.fv = f;
  unsigned r = x.u + 0x7FFFu + ((x.u >> 16) & 1u);
  return (short)(r >> 16);
}

__device__ __forceinline__ int cvtpk(float lo, float hi) {
  int r;
  asm("v_cvt_pk_bf16_f32 %0, %1, %2" : "=v"(r) : "v"(lo), "v"(hi));
  return r;
}

__device__ __forceinline__ facc_t mfma16(bfrag_t a, bfrag_t b, facc_t c) {
  return __builtin_amdgcn_mfma_f32_16x16x32_bf16(a, b, c, 0, 0, 0);
}
__device__ __forceinline__ f16acc_t mfma32(bfrag_t a, bfrag_t b, f16acc_t c) {
  return __builtin_amdgcn_mfma_f32_32x32x16_bf16(a, b, c, 0, 0, 0);
}

// ---- transpose weights to bf16: WT[p][e][d] = W_p[d][e] --------------------
__global__ void wt_kernel(const float* __restrict__ Wq, const float* __restrict__ Wk,
                          const float* __restrict__ Wv, short* __restrict__ WT) {
  const int p = blockIdx.x >> 4;
  const float* W = (p == 0) ? Wq : ((p == 1) ? Wk : Wv);
  short* o = WT + p * (D_ * D_);
  const int e = (blockIdx.x & 15) * 16 + (threadIdx.x >> 4);
  const int td = threadIdx.x & 15;
  #pragma unroll
  for (int dd = 0; dd < 16; ++dd) {
    int d = td * 16 + dd;
    o[e * D_ + d] = f2bf(W[d * D_ + e]);
  }
}

// ---- QKV projection. V stored transposed + slot-permuted per 32-kv group:
//   VT[d][kv0 + p] = V[kv0 + perm(p)][d],
//   perm(p) = 16*(p>>4) + 4*((p>>3)&1) + (p&3) + 8*((p>>2)&1)
__global__ __launch_bounds__(256) void proj_kernel(
    const float* __restrict__ X, const short* __restrict__ WT,
    short* __restrict__ Qb, short* __restrict__ Kb, short* __restrict__ VT) {
  __shared__ __align__(16) short Vt[256 * 72];
  const int tid  = threadIdx.x;
  const int wave = tid >> 6, lane = tid & 63;
  const int lrow = lane & 15, kch = lane >> 4;
  const int p  = blockIdx.x >> 8;
  const int rb = blockIdx.x & 255;
  const int row0 = rb * 64 + wave * 16;
  const int arow = row0 + lrow;
  const int bblk = rb >> 6;

  bfrag_t af[8];
  #pragma unroll
  for (int kt = 0; kt < 8; ++kt) {
    const float* src = X + (size_t)arow * D_ + kt * 32 + kch * 8;
    float4 a = *reinterpret_cast<const float4*>(src);
    float4 b = *reinterpret_cast<const float4*>(src + 4);
    bfrag_t f;
    f[0] = f2bf(a.x); f[1] = f2bf(a.y); f[2] = f2bf(a.z); f[3] = f2bf(a.w);
    f[4] = f2bf(b.x); f[5] = f2bf(b.y); f[6] = f2bf(b.z); f[7] = f2bf(b.w);
    af[kt] = f;
  }

  const short* Wp = WT + p * (D_ * D_);
  facc_t acc[16];
  #pragma unroll
  for (int nt = 0; nt < 16; ++nt) acc[nt] = (facc_t)0.0f;
  #pragma unroll
  for (int kt = 0; kt < 8; ++kt) {
    #pragma unroll
    for (int nt = 0; nt < 16; ++nt) {
      bfrag_t bf = *reinterpret_cast<const bfrag_t*>(
          Wp + (nt * 16 + lrow) * D_ + kt * 32 + kch * 8);
      acc[nt] = mfma16(af[kt], bf, acc[nt]);
    }
  }
  if (p == 0) {
    #pragma unroll
    for (int nt = 0; nt < 16; ++nt)
      #pragma unroll
      for (int r = 0; r < 4; ++r)
        Qb[(size_t)(row0 + kch * 4 + r) * D_ + nt * 16 + lrow] =
            f2bf(acc[nt][r] * 0.0625f);   // fold 1/sqrt(256)
  } else if (p == 1) {
    #pragma unroll
    for (int nt = 0; nt < 16; ++nt)
      #pragma unroll
      for (int r = 0; r < 4; ++r)
        Kb[(size_t)(row0 + kch * 4 + r) * D_ + nt * 16 + lrow] = f2bf(acc[nt][r]);
  } else {
    // kv_local = wave*16 + kch*4 + r -> stored position
    // (wave>>1)*32 + (wave&1)*16 + (kch&1)*8 + (kch>>1)*4 + r
    #pragma unroll
    for (int nt = 0; nt < 16; ++nt)
      #pragma unroll
      for (int r = 0; r < 4; ++r)
        Vt[(nt * 16 + lrow) * 72 + (wave >> 1) * 32 + (wave & 1) * 16 +
           (kch & 1) * 8 + (kch >> 1) * 4 + r] = f2bf(acc[nt][r]);
    __syncthreads();
    const int d = tid;
    const int s0 = (rb & 63) * 64;
    short* dst = VT + ((size_t)(bblk * D_ + d)) * S_ + s0;
    #pragma unroll
    for (int j = 0; j < 8; ++j)
      *reinterpret_cast<bfrag_t*>(dst + j * 8) =
          *reinterpret_cast<const bfrag_t*>(&Vt[d * 72 + j * 8]);
  }
}

// ---- flash attention, 32 q/wave via 32x32x16 MFMA, kv-split template -------
// Swapped QK^T: S^T col=lane&31=q, row=kv=(reg&3)+8*(reg>>2)+4*hi.
// P regs feed PV B-operand directly; V slot-permuted so A-frag is one b128.
template<int SPLIT>
__global__ __launch_bounds__(256, 2) void attn32(
    const short* __restrict__ Qb, const short* __restrict__ Kb,
    const short* __restrict__ VT, float* __restrict__ P0,
    float* __restrict__ PX, float2* __restrict__ ML) {
  // K tile [32 kv][256 d] (512B rows, byte ^= (kv&7)<<4)
  // V tile [256 d][32 slots] (64B rows, byte ^= ((d>>1)&3)<<4)
  __shared__ __align__(16) short Kl[2][32 * 256];
  __shared__ __align__(16) short Vl[2][256 * 32];
  const int tid  = threadIdx.x;
  const int wave = tid >> 6, lane = tid & 63;
  const int l31 = lane & 31, hi = lane >> 5;
  const int ksw = (lane & 7) << 4;
  const int vsw = ((l31 >> 1) & 3) << 4;
  const int hw = blockIdx.x;
  const int g = hw & 7, rest = hw >> 3;
  int b, part, qblk;
  if constexpr (SPLIT == 4)      { b = g >> 1; part = (g & 1) * 2 + (rest & 1); qblk = rest >> 1; }
  else if constexpr (SPLIT == 2) { b = g >> 1; part = g & 1;                    qblk = rest; }
  else                           { b = g >> 1; part = 0;                qblk = (g & 1) * 16 + rest; }
  const int q0 = qblk * 128 + wave * 32;
  const int kvbase = part * (S_ / SPLIT);
  constexpr int STEPS = (S_ / SPLIT) / 32;

  const short* Kbp = Kb + (size_t)b * S_ * D_ + (size_t)kvbase * D_;
  const short* Vbp = VT + (size_t)b * D_ * S_ + kvbase;

  // Q as B-operand: col = l31 (q), k-slot hi*8+e -> d = kt*16 + hi*8 + e
  bfrag_t qf[16];
  const short* Qp = Qb + ((size_t)b * S_ + q0 + l31) * D_;
  #pragma unroll
  for (int kt = 0; kt < 16; ++kt)
    qf[kt] = *reinterpret_cast<const bfrag_t*>(Qp + kt * 16 + hi * 8);

  auto stage = [&](int bf, int kv0) {
    #pragma unroll
    for (int j = 0; j < 4; ++j) {           // K 16 KB
      int L = j * 4096 + tid * 16;
      int row = L >> 9;
      int cs = (L & 511) ^ ((row & 7) << 4);
      const short* src = Kbp + (size_t)(kv0 + row) * D_ + (cs >> 1);
      short* dst = &Kl[bf][(j * 4096 + wave * 1024) >> 1];
      __builtin_amdgcn_global_load_lds((gas_v*)src, (las_v*)dst, 16, 0, 0);
    }
    #pragma unroll
    for (int j = 0; j < 4; ++j) {           // V 16 KB
      int L = j * 4096 + tid * 16;
      int d = L >> 6;
      int cs = (L & 63) ^ (((d >> 1) & 3) << 4);
      const short* src = Vbp + (size_t)d * S_ + kv0 + (cs >> 1);
      short* dst = &Vl[bf][(j * 4096 + wave * 1024) >> 1];
      __builtin_amdgcn_global_load_lds((gas_v*)src, (las_v*)dst, 16, 0, 0);
    }
  };

  f16acc_t o32[8];
  #pragma unroll
  for (int nt = 0; nt < 8; ++nt) o32[nt] = (f16acc_t)0.0f;
  float mrow = -3.0e38f, lsum = 0.0f;

  stage(0, 0);
  asm volatile("s_waitcnt vmcnt(0)" ::: "memory");
  __syncthreads();
  int buf = 0;

  #pragma unroll 1
  for (int t = 0; t < STEPS; ++t) {
    if (t < STEPS - 1) stage(buf ^ 1, (t + 1) * 32);
    // ---- S^T = K Q^T : 16 kt of 32x32x16 ----
    f16acc_t s16 = (f16acc_t)0.0f;
    const char* Kbase = (const char*)&Kl[buf][0];
    __builtin_amdgcn_s_setprio(1);
    #pragma unroll
    for (int kt = 0; kt < 16; ++kt) {
      bfrag_t kf = *reinterpret_cast<const bfrag_t*>(
          Kbase + l31 * 512 + ((kt * 32 + hi * 16) ^ ksw));
      s16 = mfma32(kf, qf[kt], s16);
    }
    __builtin_amdgcn_s_setprio(0);
    // ---- softmax: lane owns q = q0+l31; 16 kv in regs; one shfl ----
    float mx = s16[0];
    #pragma unroll
    for (int i = 1; i < 16; ++i) mx = fmaxf(mx, s16[i]);
    mx = fmaxf(mx, __shfl_xor(mx, 32));
    if (mx > mrow + 8.0f) {                 // defer-max rescale
      float sf = __expf(mrow - mx);
      mrow = mx;
      lsum *= sf;
      #pragma unroll
      for (int nt = 0; nt < 8; ++nt) o32[nt] *= sf;
    }
    float pe[16];
    float ls = 0.0f;
    #pragma unroll
    for (int i = 0; i < 16; ++i) {
      pe[i] = __expf(s16[i] - mrow);
      ls += pe[i];
    }
    lsum += ls;
    // ---- P -> bf16 B-frags (register-order; cvt_pk pairs) ----
    i4_t w0, w1;
    w0.x = cvtpk(pe[0], pe[1]);  w0.y = cvtpk(pe[2], pe[3]);
    w0.z = cvtpk(pe[4], pe[5]);  w0.w = cvtpk(pe[6], pe[7]);
    w1.x = cvtpk(pe[8], pe[9]);  w1.y = cvtpk(pe[10], pe[11]);
    w1.z = cvtpk(pe[12], pe[13]); w1.w = cvtpk(pe[14], pe[15]);
    bfrag_t pb0 = __builtin_bit_cast(bfrag_t, w0);
    bfrag_t pb1 = __builtin_bit_cast(bfrag_t, w1);
    // ---- O^T += V^T P^T : 8 d-blocks x 2 ----
    const char* Vbase = (const char*)&Vl[buf][0];
    __builtin_amdgcn_s_setprio(1);
    #pragma unroll
    for (int nt = 0; nt < 8; ++nt) {
      const char* vb = Vbase + (nt * 32 + l31) * 64;
      bfrag_t v0 = *reinterpret_cast<const bfrag_t*>(vb + ((hi * 16) ^ vsw));
      o32[nt] = mfma32(v0, pb0, o32[nt]);
      bfrag_t v1 = *reinterpret_cast<const bfrag_t*>(vb + ((32 + hi * 16) ^ vsw));
      o32[nt] = mfma32(v1, pb1, o32[nt]);
    }
    __builtin_amdgcn_s_setprio(0);
    asm volatile("s_waitcnt vmcnt(0)" ::: "memory");
    __syncthreads();
    buf ^= 1;
  }

  // ---- epilogue ----
  lsum += __shfl_xor(lsum, 32);
  float* Pd = (SPLIT == 1 || part == 0)
                  ? P0 : PX + (size_t)(part - 1) * ((size_t)B_ * S_ * D_);
  float* Og = Pd + ((size_t)b * S_ + q0 + l31) * D_;
  if constexpr (SPLIT == 1) {
    float inv = 1.0f / lsum;
    #pragma unroll
    for (int nt = 0; nt < 8; ++nt)
      #pragma unroll
      for (int gg = 0; gg < 4; ++gg) {
        float4 o;
        o.x = o32[nt][gg * 4 + 0] * inv; o.y = o32[nt][gg * 4 + 1] * inv;
        o.z = o32[nt][gg * 4 + 2] * inv; o.w = o32[nt][gg * 4 + 3] * inv;
        *reinterpret_cast<float4*>(Og + nt * 32 + hi * 4 + gg * 8) = o;
      }
  } else {
    #pragma unroll
    for (int nt = 0; nt < 8; ++nt)
      #pragma unroll
      for (int gg = 0; gg < 4; ++gg) {
        float4 o;
        o.x = o32[nt][gg * 4 + 0]; o.y = o32[nt][gg * 4 + 1];
        o.z = o32[nt][gg * 4 + 2]; o.w = o32[nt][gg * 4 + 3];
        *reinterpret_cast<float4*>(Og + nt * 32 + hi * 4 + gg * 8) = o;
      }
    if (lane < 32) {
      float2 ml; ml.x = mrow; ml.y = lsum;
      ML[part * (B_ * S_) + b * S_ + q0 + l31] = ml;
    }
  }
}

// ---- combine SPLIT kv-part partials ----------------------------------------
template<int SPLIT>
__global__ __launch_bounds__(256) void combineN(
    const float* __restrict__ PX, const float2* __restrict__ ML,
    float* __restrict__ Out) {
  const int r = blockIdx.x * 4 + (threadIdx.x >> 6);
  const int d4 = (threadIdx.x & 63) * 4;
  float2 ml[SPLIT];
  #pragma unroll
  for (int p = 0; p < SPLIT; ++p) ml[p] = ML[p * (B_ * S_) + r];
  float m = ml[0].x;
  #pragma unroll
  for (int p = 1; p < SPLIT; ++p) m = fmaxf(m, ml[p].x);
  float w[SPLIT];
  float denom = 0.0f;
  #pragma unroll
  for (int p = 0; p < SPLIT; ++p) {
    w[p] = __expf(ml[p].x - m);
    denom += ml[p].y * w[p];
  }
  float inv = 1.0f / denom;
  size_t idx = (size_t)r * D_ + d4;
  float4 x = *reinterpret_cast<float4*>(Out + idx);
  float4 acc;
  acc.x = x.x * w[0]; acc.y = x.y * w[0]; acc.z = x.z * w[0]; acc.w = x.w * w[0];
  #pragma unroll
  for (int p = 1; p < SPLIT; ++p) {
    float4 y = *reinterpret_cast<const float4*>(
        PX + (size_t)(p - 1) * ((size_t)B_ * S_ * D_) + idx);
    acc.x += y.x * w[p]; acc.y += y.y * w[p];
    acc.z += y.z * w[p]; acc.w += y.w * w[p];
  }
  acc.x *= inv; acc.y *= inv; acc.z *= inv; acc.w *= inv;
  *reinterpret_cast<float4*>(Out + idx) = acc;
}

extern "C" void kernel_launch(void* const* d_in, const int* in_sizes, int n_in,
                              void* d_out, int out_size, void* d_ws, size_t ws_size,
                              hipStream_t stream) {
  const float* X  = (const float*)d_in[0];
  const float* Wq = (const float*)d_in[1];
  const float* Wk = (const float*)d_in[2];
  const float* Wv = (const float*)d_in[3];
  float* out = (float*)d_out;

  char* ws = (char*)d_ws;
  short* Qb = (short*)(ws);                       // 8 MB
  short* Kb = (short*)(ws + 8388608);             // 8 MB
  short* VT = (short*)(ws + 16777216);            // 8 MB (V^T, slot-permuted)
  short* WT = (short*)(ws + 25165824);            // 384 KB
  float2* ML = (float2*)(ws + 25690112);          // 512 KB (m,l per part)
  float* PX  = (float*)(ws + 26214400);           // up to 3 x 16 MB partials
  const size_t NP = (size_t)B_ * S_ * D_ * 4;
  const size_t need4 = 26214400 + 3 * NP;
  const size_t need2 = 26214400 + 1 * NP;

  wt_kernel<<<48, 256, 0, stream>>>(Wq, Wk, Wv, WT);
  proj_kernel<<<768, 256, 0, stream>>>(X, WT, Qb, Kb, VT);
  if (ws_size >= need4) {
    attn32<4><<<512, 256, 0, stream>>>(Qb, Kb, VT, out, PX, ML);
    combineN<4><<<(B_ * S_) / 4, 256, 0, stream>>>(PX, ML, out);
  } else if (ws_size >= need2) {
    attn32<2><<<256, 256, 0, stream>>>(Qb, Kb, VT, out, PX, ML);
    combineN<2><<<(B_ * S_) / 4, 256, 0, stream>>>(PX, ML, out);
  } else {
    attn32<1><<<128, 256, 0, stream>>>(Qb, Kb, VT, out, PX, (float2*)out);
  }
}

// Round 10
// 156.950 us; speedup vs baseline: 2.0369x; 1.0196x over previous
//
#include <hip/hip_runtime.h>
#include <hip/hip_bf16.h>

typedef __attribute__((ext_vector_type(8))) short bfrag_t;
typedef __attribute__((ext_vector_type(4))) short s4_t;
typedef __attribute__((ext_vector_type(4))) float facc_t;
typedef __attribute__((ext_vector_type(16))) float f16acc_t;
typedef __attribute__((ext_vector_type(4))) int i4_t;

#define B_ 4
#define S_ 4096
#define D_ 256

using gas_v = const __attribute__((address_space(1))) void;
using las_v = __attribute__((address_space(3))) void;

__device__ __forceinline__ short f2bf(float f) {
  union { float fv; unsigned u; } x; x.fv = f;
  unsigned r = x.u + 0x7FFFu + ((x.u >> 16) & 1u);
  return (short)(r >> 16);
}

__device__ __forceinline__ int cvtpk(float lo, float hi) {
  int r;
  asm("v_cvt_pk_bf16_f32 %0, %1, %2" : "=v"(r) : "v"(lo), "v"(hi));
  return r;
}

__device__ __forceinline__ facc_t mfma16(bfrag_t a, bfrag_t b, facc_t c) {
  return __builtin_amdgcn_mfma_f32_16x16x32_bf16(a, b, c, 0, 0, 0);
}
__device__ __forceinline__ f16acc_t mfma32(bfrag_t a, bfrag_t b, f16acc_t c) {
  return __builtin_amdgcn_mfma_f32_32x32x16_bf16(a, b, c, 0, 0, 0);
}

// ---- transpose weights to bf16: WT[p][e][d] = W_p[d][e] --------------------
__global__ void wt_kernel(const float* __restrict__ Wq, const float* __restrict__ Wk,
                          const float* __restrict__ Wv, short* __restrict__ WT) {
  const int p = blockIdx.x >> 4;
  const float* W = (p == 0) ? Wq : ((p == 1) ? Wk : Wv);
  short* o = WT + p * (D_ * D_);
  const int e = (blockIdx.x & 15) * 16 + (threadIdx.x >> 4);
  const int td = threadIdx.x & 15;
  #pragma unroll
  for (int dd = 0; dd < 16; ++dd) {
    int d = td * 16 + dd;
    o[e * D_ + d] = f2bf(W[d * D_ + e]);
  }
}

// ---- fused QKV projection: X read ONCE, all outputs staged via LDS ---------
// V stored transposed + slot-permuted per 32-kv group (as round 9):
//   kv_local = wave*16+kch*4+r  -> col (wave>>1)*32+(wave&1)*16+(kch&1)*8+(kch>>1)*4+r
__global__ __launch_bounds__(256) void proj_kernel(
    const float* __restrict__ X, const short* __restrict__ WT,
    short* __restrict__ Qb, short* __restrict__ Kb, short* __restrict__ VT) {
  __shared__ __align__(16) short Stg[256 * 72];   // 36.9 KB union buffer
  const int tid  = threadIdx.x;
  const int wave = tid >> 6, lane = tid & 63;
  const int lrow = lane & 15, kch = lane >> 4;
  const int rb = blockIdx.x;                      // 0..255
  const int row0 = rb * 64 + wave * 16;
  const int arow = row0 + lrow;
  const int bblk = rb >> 6;

  // A-frags from X, loaded once for all three projections
  bfrag_t af[8];
  #pragma unroll
  for (int kt = 0; kt < 8; ++kt) {
    const float* src = X + (size_t)arow * D_ + kt * 32 + kch * 8;
    float4 a = *reinterpret_cast<const float4*>(src);
    float4 b = *reinterpret_cast<const float4*>(src + 4);
    bfrag_t f;
    f[0] = f2bf(a.x); f[1] = f2bf(a.y); f[2] = f2bf(a.z); f[3] = f2bf(a.w);
    f[4] = f2bf(b.x); f[5] = f2bf(b.y); f[6] = f2bf(b.z); f[7] = f2bf(b.w);
    af[kt] = f;
  }

  #pragma unroll 1
  for (int p = 0; p < 3; ++p) {
    const short* Wp = WT + p * (D_ * D_);
    facc_t acc[16];
    #pragma unroll
    for (int nt = 0; nt < 16; ++nt) acc[nt] = (facc_t)0.0f;
    #pragma unroll
    for (int kt = 0; kt < 8; ++kt) {
      #pragma unroll
      for (int nt = 0; nt < 16; ++nt) {
        bfrag_t bf = *reinterpret_cast<const bfrag_t*>(
            Wp + (nt * 16 + lrow) * D_ + kt * 32 + kch * 8);
        acc[nt] = mfma16(af[kt], bf, acc[nt]);
      }
    }
    __syncthreads();                              // protect prior read-out
    if (p < 2) {
      const float sc = (p == 0) ? 0.0625f : 1.0f; // fold 1/sqrt(256) into Q
      // stage row-major [64][264]
      #pragma unroll
      for (int nt = 0; nt < 16; ++nt)
        #pragma unroll
        for (int r = 0; r < 4; ++r)
          Stg[(wave * 16 + kch * 4 + r) * 264 + nt * 16 + lrow] =
              f2bf(acc[nt][r] * sc);
      __syncthreads();
      short* dstbase = ((p == 0) ? Qb : Kb) + (size_t)rb * 64 * D_;
      #pragma unroll
      for (int k = 0; k < 8; ++k) {
        int c = k * 256 + tid;                    // chunk 0..2047
        int row = c >> 5, col = c & 31;
        *reinterpret_cast<bfrag_t*>(dstbase + row * D_ + col * 8) =
            *reinterpret_cast<const bfrag_t*>(&Stg[row * 264 + col * 8]);
      }
    } else {
      // stage transposed+permuted [256][72], 4-short packed writes
      #pragma unroll
      for (int nt = 0; nt < 16; ++nt) {
        s4_t v;
        #pragma unroll
        for (int r = 0; r < 4; ++r) v[r] = f2bf(acc[nt][r]);
        *reinterpret_cast<s4_t*>(
            &Stg[(nt * 16 + lrow) * 72 + (wave >> 1) * 32 + (wave & 1) * 16 +
                 (kch & 1) * 8 + (kch >> 1) * 4]) = v;
      }
      __syncthreads();
      const int d = tid;
      const int s0 = (rb & 63) * 64;
      short* dst = VT + ((size_t)(bblk * D_ + d)) * S_ + s0;
      #pragma unroll
      for (int j = 0; j < 8; ++j)
        *reinterpret_cast<bfrag_t*>(dst + j * 8) =
            *reinterpret_cast<const bfrag_t*>(&Stg[d * 72 + j * 8]);
    }
  }
}

// ---- flash attention: 8 waves x 32 q, 3-buffer counted-vmcnt pipeline ------
// Swapped QK^T (32x32x16): lane owns q=q0+l31; P regs feed PV B directly.
template<int SPLIT>
__global__ __launch_bounds__(512, 2) void attn32(
    const short* __restrict__ Qb, const short* __restrict__ Kb,
    const short* __restrict__ VT, float* __restrict__ P0,
    float* __restrict__ PX, float2* __restrict__ ML) {
  // K tile [32 kv][256 d] (512B rows, byte ^= (kv&7)<<4)
  // V tile [256 d][32 slots] (64B rows, byte ^= ((d>>1)&3)<<4)
  __shared__ __align__(16) short Kl[3][32 * 256];
  __shared__ __align__(16) short Vl[3][256 * 32];
  const int tid  = threadIdx.x;
  const int wave = tid >> 6, lane = tid & 63;
  const int l31 = lane & 31, hi = lane >> 5;
  const int ksw = (lane & 7) << 4;
  const int vsw = ((l31 >> 1) & 3) << 4;
  const int hw = blockIdx.x;
  const int xcd = hw & 7, i = hw >> 3;
  int b, part, qblk;
  if constexpr (SPLIT == 4) {                     // 256 blocks
    int combo = (i & 1) * 8 + xcd;                // (b,part) pinned to XCD
    b = combo >> 2; part = combo & 3; qblk = i >> 1;
  } else if constexpr (SPLIT == 2) {              // 128 blocks
    b = xcd >> 1; part = xcd & 1; qblk = i;
  } else {                                        // 64 blocks
    b = hw >> 4; part = 0; qblk = hw & 15;
  }
  const int q0 = qblk * 256 + wave * 32;
  const int kvbase = part * (S_ / SPLIT);
  constexpr int STEPS = (S_ / SPLIT) / 32;

  const short* Kbp = Kb + (size_t)b * S_ * D_ + (size_t)kvbase * D_;
  const short* Vbp = VT + (size_t)b * D_ * S_ + kvbase;

  // Q as B-operand: col=l31, k-slot hi*8+e -> d = kt*16 + hi*8 + e
  bfrag_t qf[16];
  const short* Qp = Qb + ((size_t)b * S_ + q0 + l31) * D_;
  #pragma unroll
  for (int kt = 0; kt < 16; ++kt)
    qf[kt] = *reinterpret_cast<const bfrag_t*>(Qp + kt * 16 + hi * 8);

  // stage one 32-kv tile (K 16KB + V 16KB): 4 x 16B DMA per thread (512 thr)
  auto stage = [&](int bf, int kv0) {
    #pragma unroll
    for (int j = 0; j < 2; ++j) {
      int L = j * 8192 + tid * 16;
      int row = L >> 9;
      int cs = (L & 511) ^ ((row & 7) << 4);
      const short* src = Kbp + (size_t)(kv0 + row) * D_ + (cs >> 1);
      short* dst = &Kl[bf][(j * 8192 + wave * 1024) >> 1];
      __builtin_amdgcn_global_load_lds((gas_v*)src, (las_v*)dst, 16, 0, 0);
    }
    #pragma unroll
    for (int j = 0; j < 2; ++j) {
      int L = j * 8192 + tid * 16;
      int d = L >> 6;
      int cs = (L & 63) ^ (((d >> 1) & 3) << 4);
      const short* src = Vbp + (size_t)d * S_ + kv0 + (cs >> 1);
      short* dst = &Vl[bf][(j * 8192 + wave * 1024) >> 1];
      __builtin_amdgcn_global_load_lds((gas_v*)src, (las_v*)dst, 16, 0, 0);
    }
  };

  f16acc_t o32[8];
  #pragma unroll
  for (int nt = 0; nt < 8; ++nt) o32[nt] = (f16acc_t)0.0f;
  float mrow = -3.0e38f, lsum = 0.0f;

  stage(0, 0);
  stage(1, 32);

  #pragma unroll 1
  for (int t = 0; t < STEPS; ++t) {
    const int buf = t % 3;
    // counted wait: own stage(t) retired (4 newest = stage(t+1) may fly)
    if (t < STEPS - 1) {
      asm volatile("s_waitcnt vmcnt(4)" ::: "memory");
    } else {
      asm volatile("s_waitcnt vmcnt(0)" ::: "memory");
    }
    __builtin_amdgcn_sched_barrier(0);
    __builtin_amdgcn_s_barrier();                 // everyone's stage(t) landed
    __builtin_amdgcn_sched_barrier(0);
    if (t + 2 < STEPS) stage((t + 2) % 3, (t + 2) * 32);
    // ---- S^T = K Q^T : 16 kt of 32x32x16 ----
    f16acc_t s16 = (f16acc_t)0.0f;
    const char* Kbase = (const char*)&Kl[buf][0];
    __builtin_amdgcn_s_setprio(1);
    #pragma unroll
    for (int kt = 0; kt < 16; ++kt) {
      bfrag_t kf = *reinterpret_cast<const bfrag_t*>(
          Kbase + l31 * 512 + ((kt * 32 + hi * 16) ^ ksw));
      s16 = mfma32(kf, qf[kt], s16);
    }
    __builtin_amdgcn_s_setprio(0);
    // ---- softmax: lane-local 16 kv; one shfl ----
    float mx = s16[0];
    #pragma unroll
    for (int i2 = 1; i2 < 16; ++i2) mx = fmaxf(mx, s16[i2]);
    mx = fmaxf(mx, __shfl_xor(mx, 32));
    if (mx > mrow + 8.0f) {                       // defer-max rescale
      float sf = __expf(mrow - mx);
      mrow = mx;
      lsum *= sf;
      #pragma unroll
      for (int nt = 0; nt < 8; ++nt) o32[nt] *= sf;
    }
    float ls = 0.0f;
    #pragma unroll
    for (int i2 = 0; i2 < 16; ++i2) {
      float e = __expf(s16[i2] - mrow);
      s16[i2] = e;                                // reuse regs
      ls += e;
    }
    lsum += ls;
    i4_t w0, w1;
    w0.x = cvtpk(s16[0], s16[1]);   w0.y = cvtpk(s16[2], s16[3]);
    w0.z = cvtpk(s16[4], s16[5]);   w0.w = cvtpk(s16[6], s16[7]);
    w1.x = cvtpk(s16[8], s16[9]);   w1.y = cvtpk(s16[10], s16[11]);
    w1.z = cvtpk(s16[12], s16[13]); w1.w = cvtpk(s16[14], s16[15]);
    bfrag_t pb0 = __builtin_bit_cast(bfrag_t, w0);
    bfrag_t pb1 = __builtin_bit_cast(bfrag_t, w1);
    // ---- O^T += V^T P^T ----
    const char* Vbase = (const char*)&Vl[buf][0];
    __builtin_amdgcn_s_setprio(1);
    #pragma unroll
    for (int nt = 0; nt < 8; ++nt) {
      const char* vb = Vbase + (nt * 32 + l31) * 64;
      bfrag_t v0 = *reinterpret_cast<const bfrag_t*>(vb + ((hi * 16) ^ vsw));
      o32[nt] = mfma32(v0, pb0, o32[nt]);
      bfrag_t v1 = *reinterpret_cast<const bfrag_t*>(vb + ((32 + hi * 16) ^ vsw));
      o32[nt] = mfma32(v1, pb1, o32[nt]);
    }
    __builtin_amdgcn_s_setprio(0);
  }

  // ---- epilogue ----
  lsum += __shfl_xor(lsum, 32);
  float* Pd = (SPLIT == 1 || part == 0)
                  ? P0 : PX + (size_t)(part - 1) * ((size_t)B_ * S_ * D_);
  float* Og = Pd + ((size_t)b * S_ + q0 + l31) * D_;
  if constexpr (SPLIT == 1) {
    float inv = 1.0f / lsum;
    #pragma unroll
    for (int nt = 0; nt < 8; ++nt)
      #pragma unroll
      for (int gg = 0; gg < 4; ++gg) {
        float4 o;
        o.x = o32[nt][gg * 4 + 0] * inv; o.y = o32[nt][gg * 4 + 1] * inv;
        o.z = o32[nt][gg * 4 + 2] * inv; o.w = o32[nt][gg * 4 + 3] * inv;
        *reinterpret_cast<float4*>(Og + nt * 32 + hi * 4 + gg * 8) = o;
      }
  } else {
    #pragma unroll
    for (int nt = 0; nt < 8; ++nt)
      #pragma unroll
      for (int gg = 0; gg < 4; ++gg) {
        float4 o;
        o.x = o32[nt][gg * 4 + 0]; o.y = o32[nt][gg * 4 + 1];
        o.z = o32[nt][gg * 4 + 2]; o.w = o32[nt][gg * 4 + 3];
        *reinterpret_cast<float4*>(Og + nt * 32 + hi * 4 + gg * 8) = o;
      }
    if (lane < 32) {
      float2 ml; ml.x = mrow; ml.y = lsum;
      ML[part * (B_ * S_) + b * S_ + q0 + l31] = ml;
    }
  }
}

// ---- combine SPLIT kv-part partials ----------------------------------------
template<int SPLIT>
__global__ __launch_bounds__(256) void combineN(
    const float* __restrict__ PX, const float2* __restrict__ ML,
    float* __restrict__ Out) {
  const int r = blockIdx.x * 4 + (threadIdx.x >> 6);
  const int d4 = (threadIdx.x & 63) * 4;
  float2 ml[SPLIT];
  #pragma unroll
  for (int p = 0; p < SPLIT; ++p) ml[p] = ML[p * (B_ * S_) + r];
  float m = ml[0].x;
  #pragma unroll
  for (int p = 1; p < SPLIT; ++p) m = fmaxf(m, ml[p].x);
  float w[SPLIT];
  float denom = 0.0f;
  #pragma unroll
  for (int p = 0; p < SPLIT; ++p) {
    w[p] = __expf(ml[p].x - m);
    denom += ml[p].y * w[p];
  }
  float inv = 1.0f / denom;
  size_t idx = (size_t)r * D_ + d4;
  float4 x = *reinterpret_cast<float4*>(Out + idx);
  float4 acc;
  acc.x = x.x * w[0]; acc.y = x.y * w[0]; acc.z = x.z * w[0]; acc.w = x.w * w[0];
  #pragma unroll
  for (int p = 1; p < SPLIT; ++p) {
    float4 y = *reinterpret_cast<const float4*>(
        PX + (size_t)(p - 1) * ((size_t)B_ * S_ * D_) + idx);
    acc.x += y.x * w[p]; acc.y += y.y * w[p];
    acc.z += y.z * w[p]; acc.w += y.w * w[p];
  }
  acc.x *= inv; acc.y *= inv; acc.z *= inv; acc.w *= inv;
  *reinterpret_cast<float4*>(Out + idx) = acc;
}

extern "C" void kernel_launch(void* const* d_in, const int* in_sizes, int n_in,
                              void* d_out, int out_size, void* d_ws, size_t ws_size,
                              hipStream_t stream) {
  const float* X  = (const float*)d_in[0];
  const float* Wq = (const float*)d_in[1];
  const float* Wk = (const float*)d_in[2];
  const float* Wv = (const float*)d_in[3];
  float* out = (float*)d_out;

  char* ws = (char*)d_ws;
  short* Qb = (short*)(ws);                       // 8 MB
  short* Kb = (short*)(ws + 8388608);             // 8 MB
  short* VT = (short*)(ws + 16777216);            // 8 MB (V^T, slot-permuted)
  short* WT = (short*)(ws + 25165824);            // 384 KB
  float2* ML = (float2*)(ws + 25690112);          // 512 KB (m,l per part)
  float* PX  = (float*)(ws + 26214400);           // up to 3 x 16 MB partials
  const size_t NP = (size_t)B_ * S_ * D_ * 4;
  const size_t need4 = 26214400 + 3 * NP;
  const size_t need2 = 26214400 + 1 * NP;

  wt_kernel<<<48, 256, 0, stream>>>(Wq, Wk, Wv, WT);
  proj_kernel<<<256, 256, 0, stream>>>(X, WT, Qb, Kb, VT);
  if (ws_size >= need4) {
    attn32<4><<<256, 512, 0, stream>>>(Qb, Kb, VT, out, PX, ML);
    combineN<4><<<(B_ * S_) / 4, 256, 0, stream>>>(PX, ML, out);
  } else if (ws_size >= need2) {
    attn32<2><<<128, 512, 0, stream>>>(Qb, Kb, VT, out, PX, ML);
    combineN<2><<<(B_ * S_) / 4, 256, 0, stream>>>(PX, ML, out);
  } else {
    attn32<1><<<64, 512, 0, stream>>>(Qb, Kb, VT, out, PX, (float2*)out);
  }
}